// Round 3
// baseline (2926.959 us; speedup 1.0000x reference)
//
#include <hip/hip_runtime.h>

// ---------------------------------------------------------------------------
// types & helpers
// ---------------------------------------------------------------------------
using bf16x8 = __attribute__((ext_vector_type(8))) short;
using f32x4  = __attribute__((ext_vector_type(4))) float;
using u16x4  = __attribute__((ext_vector_type(4))) unsigned short;
using as3_void  = __attribute__((address_space(3))) void;
using as1_cvoid = const __attribute__((address_space(1))) void;

__device__ __forceinline__ unsigned short f2bf(float x) {
    union { float f; unsigned u; } v; v.f = x;
    unsigned r = v.u + 0x7FFFu + ((v.u >> 16) & 1u);   // RNE
    return (unsigned short)(r >> 16);
}
__device__ __forceinline__ float bf2f(unsigned short h) {
    union { unsigned u; float f; } v; v.u = ((unsigned)h) << 16;
    return v.f;
}

// ---------------------------------------------------------------------------
// bf16 MFMA GEMM: Cb[M,N](bf16) = A[M,K](bf16 rm) @ Bt[N,K]^T (bf16) * scale
// BM x 128 tile, BK=64, 4 waves (2 row x 2 col). BM=128 -> m97 structure.
// Optional fused BN stats: column sum/sumsq atomicAdd into statp[0..N-1],
// statp[512..]. LDS XOR-swizzle on the GLOBAL source (global_load_lds needs
// linear dest); ds_read applies the same swizzle.
// ---------------------------------------------------------------------------
template<int BM>
__global__ __launch_bounds__(256) void gemm_bf16(
    const unsigned short* __restrict__ A, const unsigned short* __restrict__ Bt,
    int M, int N, int K,
    unsigned short* __restrict__ Cb, int ostride, int ooff,
    const float* __restrict__ scalep, float* __restrict__ statp)
{
    constexpr int WROWS = BM / 2;        // rows per row-wave
    constexpr int MI = WROWS / 16;       // i-fragments
    __shared__ __align__(16) unsigned short As[BM * 64];
    __shared__ __align__(16) unsigned short Bs[128 * 64];
    const int tid  = threadIdx.x;
    const int lane = tid & 63, wave = tid >> 6;
    const int m0 = blockIdx.x * BM, n0 = blockIdx.y * 128;
    const int wr = wave >> 1, wc = wave & 1;
    const int rl = lane & 15, kg = lane >> 4;
    f32x4 acc[MI][4] = {};

    for (int kt = 0; kt < K; kt += 64) {
#pragma unroll
        for (int it = 0; it < BM / 32; ++it) {           // A: BM*8 chunks
            int slot = it * 256 + tid;
            int r = slot >> 3, c = slot & 7;
            int cg = c ^ (r & 7);
            const unsigned short* ga = A + (size_t)(m0 + r) * K + (kt + cg * 8);
            __builtin_amdgcn_global_load_lds((as1_cvoid*)ga, (as3_void*)(As + slot * 8), 16, 0, 0);
        }
#pragma unroll
        for (int it = 0; it < 4; ++it) {                 // B: 1024 chunks
            int slot = it * 256 + tid;
            int r = slot >> 3, c = slot & 7;
            int cg = c ^ (r & 7);
            const unsigned short* gb = Bt + (size_t)(n0 + r) * K + (kt + cg * 8);
            __builtin_amdgcn_global_load_lds((as1_cvoid*)gb, (as3_void*)(Bs + slot * 8), 16, 0, 0);
        }
        __syncthreads();
#pragma unroll
        for (int kh = 0; kh < 2; ++kh) {
            bf16x8 a_[MI], b_[4];
#pragma unroll
            for (int i = 0; i < MI; ++i) {
                int ra = wr * WROWS + i * 16 + rl;
                int ca = (kh * 4 + kg) ^ (ra & 7);
                a_[i] = *reinterpret_cast<const bf16x8*>(&As[ra * 64 + ca * 8]);
            }
#pragma unroll
            for (int j = 0; j < 4; ++j) {
                int rb = wc * 64 + j * 16 + rl;
                int cb = (kh * 4 + kg) ^ (rb & 7);
                b_[j] = *reinterpret_cast<const bf16x8*>(&Bs[rb * 64 + cb * 8]);
            }
#pragma unroll
            for (int i = 0; i < MI; ++i)
#pragma unroll
                for (int j = 0; j < 4; ++j)
                    acc[i][j] = __builtin_amdgcn_mfma_f32_16x16x32_bf16(a_[i], b_[j], acc[i][j], 0, 0, 0);
        }
        __syncthreads();
    }

    const float sc = scalep ? *scalep : 1.0f;
#pragma unroll
    for (int i = 0; i < MI; ++i)
#pragma unroll
        for (int j = 0; j < 4; ++j)
#pragma unroll
            for (int e = 0; e < 4; ++e) {
                int rr = m0 + wr * WROWS + i * 16 + kg * 4 + e;
                int cc = n0 + wc * 64 + j * 16 + rl;
                Cb[(size_t)rr * ostride + ooff + cc] = f2bf(acc[i][j][e] * sc);
            }
    if (statp) {
#pragma unroll
        for (int j = 0; j < 4; ++j) {
            float s = 0.f, q = 0.f;
#pragma unroll
            for (int i = 0; i < MI; ++i)
#pragma unroll
                for (int e = 0; e < 4; ++e) {
                    float x = acc[i][j][e] * sc;
                    s += x; q += x * x;
                }
            s += __shfl_xor(s, 16); s += __shfl_xor(s, 32);
            q += __shfl_xor(q, 16); q += __shfl_xor(q, 32);
            if (kg == 0) {
                int cc = n0 + wc * 64 + j * 16 + rl;
                atomicAdd(&statp[cc], s);
                atomicAdd(&statp[512 + cc], q);
            }
        }
    }
}

// ---------------------------------------------------------------------------
// CSR build (both edge lists in one pass each)
// ---------------------------------------------------------------------------
__global__ void csr_count2(const int* __restrict__ e1, int E1, int* __restrict__ c1,
                           const int* __restrict__ e2, int E2, int* __restrict__ c2) {
    int i = blockIdx.x * 256 + threadIdx.x;
    if (i < E1) atomicAdd(&c1[e1[i]], 1);
    else if (i < E1 + E2) atomicAdd(&c2[e2[i - E1]], 1);
}

__global__ void csr_scan2(const int* __restrict__ cnt1, int n1, int* __restrict__ offs1, int* __restrict__ cur1,
                          const int* __restrict__ cnt2, int n2, int* __restrict__ offs2, int* __restrict__ cur2) {
    const int* cnt = blockIdx.x ? cnt2 : cnt1;
    int n           = blockIdx.x ? n2 : n1;
    int* offs       = blockIdx.x ? offs2 : offs1;
    int* cursor     = blockIdx.x ? cur2 : cur1;
    __shared__ int part[1024];
    int t = threadIdx.x;
    int per = n >> 10;
    int base = t * per;
    int loc[8];
    int s = 0;
    for (int j = 0; j < per; ++j) { loc[j] = s; s += cnt[base + j]; }
    part[t] = s;
    __syncthreads();
    for (int o = 1; o < 1024; o <<= 1) {
        int v = (t >= o) ? part[t - o] : 0;
        __syncthreads();
        part[t] += v;
        __syncthreads();
    }
    int excl = (t == 0) ? 0 : part[t - 1];
    for (int j = 0; j < per; ++j) {
        int v = excl + loc[j];
        offs[base + j] = v;
        cursor[base + j] = v;
    }
    if (t == 1023) offs[n] = part[1023];
}

__global__ void csr_fill2(const int* __restrict__ e1, int E1, int* __restrict__ cur1, int* __restrict__ s1,
                          const int* __restrict__ e2, int E2, int* __restrict__ cur2, int* __restrict__ s2) {
    int i = blockIdx.x * 256 + threadIdx.x;
    if (i < E1) {
        int d = e1[i], s = e1[E1 + i];
        s1[atomicAdd(&cur1[d], 1)] = s;
    } else if (i < E1 + E2) {
        int e = i - E1;
        int d = e2[e], s = e2[E2 + e];
        s2[atomicAdd(&cur2[d], 1)] = s;
    }
}

// ---------------------------------------------------------------------------
// fused gather + BN stats, bf16 in/out (512 cols).
// T[i,:] = sum_{e in in(i)} Y[src_e,:] + (1+eps[l]) * Y[i,:]
// block = nrows rows x 128 threads(x4 cols); 8 atomics/thread at the end.
// ---------------------------------------------------------------------------
__global__ void gather_stats(const u16x4* __restrict__ Y, const int* __restrict__ offs,
                             const int* __restrict__ srcs, const float* __restrict__ epsv,
                             int l, u16x4* __restrict__ T, float* __restrict__ ss, int nrows) {
    int c = threadIdx.x;
    int r0 = blockIdx.x * nrows;
    float e = 1.0f + epsv[l];
    f32x4 sum = {}, sq = {};
    for (int r = 0; r < nrows; ++r) {
        int i = r0 + r;
        int lo = offs[i], hi = offs[i + 1];
        u16x4 hv = Y[(size_t)i * 128 + c];
        f32x4 acc;
#pragma unroll
        for (int j = 0; j < 4; ++j) acc[j] = e * bf2f(hv[j]);
        for (int k = lo; k < hi; ++k) {
            u16x4 sv = Y[(size_t)srcs[k] * 128 + c];
#pragma unroll
            for (int j = 0; j < 4; ++j) acc[j] += bf2f(sv[j]);
        }
        u16x4 o;
#pragma unroll
        for (int j = 0; j < 4; ++j) o[j] = f2bf(acc[j]);
        T[(size_t)i * 128 + c] = o;
        sum += acc; sq += acc * acc;
    }
#pragma unroll
    for (int j = 0; j < 4; ++j) {
        atomicAdd(&ss[c * 4 + j], sum[j]);
        atomicAdd(&ss[512 + c * 4 + j], sq[j]);
    }
}

// bn finalize+apply+ReLU, bf16 in -> bf16 out (strided, optional scale)
__global__ void bn_apply(const u16x4* __restrict__ X, int M, const float* __restrict__ ss,
                         const float* __restrict__ g, const float* __restrict__ b,
                         unsigned short* __restrict__ out, int ostride, int ooff,
                         const float* __restrict__ scale) {
    int c = threadIdx.x;                                // 128 threads x 4 cols
    float inv = 1.0f / (float)M;
    float al[4], be[4];
#pragma unroll
    for (int i = 0; i < 4; ++i) {
        float mean = ss[c * 4 + i] * inv;
        float var  = ss[512 + c * 4 + i] * inv - mean * mean;
        al[i] = g[c * 4 + i] * rsqrtf(var + 1e-5f);
        be[i] = b[c * 4 + i] - mean * al[i];
    }
    float sc = scale ? *scale : 1.0f;
    int rows = M / gridDim.x;
    int r0 = blockIdx.x * rows;
    for (int r = 0; r < rows; ++r) {
        u16x4 v = X[(size_t)(r0 + r) * 128 + c];
        u16x4 h;
#pragma unroll
        for (int i = 0; i < 4; ++i)
            h[i] = f2bf(fmaxf(al[i] * bf2f(v[i]) + be[i], 0.f) * sc);
        *reinterpret_cast<u16x4*>(out + (size_t)(r0 + r) * ostride + ooff + c * 4) = h;
    }
}

// contiguous f32 -> bf16 convert
__global__ void cvt_bf16(const f32x4* __restrict__ X, u16x4* __restrict__ out, int n4) {
    for (int i = blockIdx.x * blockDim.x + threadIdx.x; i < n4; i += gridDim.x * blockDim.x) {
        f32x4 v = X[i];
        u16x4 h;
#pragma unroll
        for (int j = 0; j < 4; ++j) h[j] = f2bf(v[j]);
        out[i] = h;
    }
}

// ---------------------------------------------------------------------------
// motif transpose: S f32 [4096][8192] -> D bf16 [8192][4096], 64x64 tiles,
// f32x4 loads / u16x4 LDS writes / u16x4 global stores.
// ---------------------------------------------------------------------------
__global__ __launch_bounds__(256) void motif_transpose(const float* __restrict__ S,
                                                       unsigned short* __restrict__ D) {
    __shared__ unsigned short tile[64][66];
    int m0 = blockIdx.x * 64;   // source col block (8192 dim)
    int k0 = blockIdx.y * 64;   // source row block (4096 dim)
    int t = threadIdx.x;
    int r = t >> 4, cq = t & 15;
#pragma unroll
    for (int p = 0; p < 4; ++p) {
        int row = r + p * 16;
        f32x4 v = *reinterpret_cast<const f32x4*>(S + (size_t)(k0 + row) * 8192 + m0 + cq * 4);
        u16x4 h;
#pragma unroll
        for (int j = 0; j < 4; ++j) h[j] = f2bf(v[j]);
        *reinterpret_cast<u16x4*>(&tile[row][cq * 4]) = h;
    }
    __syncthreads();
#pragma unroll
    for (int p = 0; p < 4; ++p) {
        int col = r + p * 16;   // dest row = m0+col
        u16x4 h;
#pragma unroll
        for (int i = 0; i < 4; ++i) h[i] = tile[cq * 4 + i][col];
        *reinterpret_cast<u16x4*>(D + (size_t)(m0 + col) * 4096 + k0 + cq * 4) = h;
    }
}

// ---------------------------------------------------------------------------
// small transposes (weights), batched
// ---------------------------------------------------------------------------
__global__ void transpose_cvt_b(const float* __restrict__ S, unsigned short* __restrict__ D,
                                int rows, int cols, size_t sstride, size_t dstride) {
    S += blockIdx.z * sstride; D += blockIdx.z * dstride;
    __shared__ unsigned short tile[32][33];
    int x0 = blockIdx.x * 32, y0 = blockIdx.y * 32;
    for (int j = threadIdx.y; j < 32; j += blockDim.y)
        tile[j][threadIdx.x] = f2bf(S[(size_t)(y0 + j) * cols + x0 + threadIdx.x]);
    __syncthreads();
    for (int j = threadIdx.y; j < 32; j += blockDim.y)
        D[(size_t)(x0 + j) * rows + y0 + threadIdx.x] = tile[threadIdx.x][j];
}

// 11 square 512x512 weights in one launch: z<4 -> m1W2, z<7 -> m2W1r, else m2W2
__global__ void transpose_cvt11(const float* __restrict__ A, unsigned short* __restrict__ Ad,
                                const float* __restrict__ B, unsigned short* __restrict__ Bd,
                                const float* __restrict__ Cs, unsigned short* __restrict__ Cd) {
    int z = blockIdx.z;
    const float* S; unsigned short* D;
    if (z < 4)      { S = A  + (size_t)z * 262144;       D = Ad + (size_t)z * 262144; }
    else if (z < 7) { S = B  + (size_t)(z - 4) * 262144; D = Bd + (size_t)(z - 4) * 262144; }
    else            { S = Cs + (size_t)(z - 7) * 262144; D = Cd + (size_t)(z - 7) * 262144; }
    __shared__ unsigned short tile[32][33];
    int x0 = blockIdx.x * 32, y0 = blockIdx.y * 32;
    for (int j = threadIdx.y; j < 32; j += blockDim.y)
        tile[j][threadIdx.x] = f2bf(S[(size_t)(y0 + j) * 512 + x0 + threadIdx.x]);
    __syncthreads();
    for (int j = threadIdx.y; j < 32; j += blockDim.y)
        D[(size_t)(x0 + j) * 512 + y0 + threadIdx.x] = tile[threadIdx.x][j];
}

__global__ void transpose_bf16(const unsigned short* __restrict__ S, unsigned short* __restrict__ D,
                               int rows, int cols) { // D[c][r] = S[r][c]
    __shared__ unsigned short tile[32][33];
    int x0 = blockIdx.x * 32, y0 = blockIdx.y * 32;
    for (int j = threadIdx.y; j < 32; j += blockDim.y)
        tile[j][threadIdx.x] = S[(size_t)(y0 + j) * cols + x0 + threadIdx.x];
    __syncthreads();
    for (int j = threadIdx.y; j < 32; j += blockDim.y)
        D[(size_t)(x0 + j) * rows + y0 + threadIdx.x] = tile[threadIdx.x][j];
}

// ---------------------------------------------------------------------------
// graph pooling (graph_ids sorted -> binary-search row range per graph)
// ---------------------------------------------------------------------------
__device__ __forceinline__ int lbound(const int* __restrict__ a, int n, int v) {
    int lo = 0, hi = n;
    while (lo < hi) { int m = (lo + hi) >> 1; if (a[m] < v) lo = m + 1; else hi = m; }
    return lo;
}

__global__ void pool_bf16(const u16x4* __restrict__ Hm, const int* __restrict__ gid,
                          int n, float* __restrict__ P) {   // 1024 cols
    int g = blockIdx.x;
    int lo = lbound(gid, n, g), hi = lbound(gid, n, g + 1);
    int c = threadIdx.x;
    f32x4 s = {};
    for (int i = lo; i < hi; ++i) {
        u16x4 v = Hm[(size_t)i * 256 + c];
#pragma unroll
        for (int j = 0; j < 4; ++j) s[j] += bf2f(v[j]);
    }
#pragma unroll
    for (int j = 0; j < 4; ++j)
        P[(size_t)g * 1024 + c * 4 + j] = s[j];
}

__global__ void pool_f32(const float* __restrict__ Hm, int cols,
                         const int* __restrict__ gid, int n, float* __restrict__ P) {
    int g = blockIdx.x;
    int lo = lbound(gid, n, g), hi = lbound(gid, n, g + 1);
    for (int c = threadIdx.x; c < cols; c += blockDim.x) {
        float s = 0.f;
        for (int i = lo; i < hi; ++i) s += Hm[(size_t)i * cols + c];
        P[(size_t)g * cols + c] = s;
    }
}

__global__ void softmax2(const float* __restrict__ atts, float* __restrict__ a) {
    if (threadIdx.x == 0) {
        float m = fmaxf(atts[0], atts[1]);
        float e0 = expf(atts[0] - m), e1 = expf(atts[1] - m);
        float inv = 1.0f / (e0 + e1);
        a[0] = e0 * inv; a[1] = e1 * inv;
    }
}

// score[g,o] = P0[g]@W0 + b0 + sum_l PL[l][g]@W[l] + b[l]
__global__ __launch_bounds__(256) void score_kernel(
    const float* __restrict__ P0, const float* __restrict__ PL,
    const float* __restrict__ W0, const float* __restrict__ b0,
    const float* __restrict__ W, const float* __restrict__ bb,
    float* __restrict__ out)
{
    int g = blockIdx.x;
    int t = threadIdx.x;
    float part[10];
#pragma unroll
    for (int o = 0; o < 10; ++o) part[o] = 0.f;
    if (t < 128) {
        float p = P0[g * 128 + t];
#pragma unroll
        for (int o = 0; o < 10; ++o) part[o] += p * W0[t * 10 + o];
    }
    for (int l = 0; l < 4; ++l) {
        const float* p = PL + (size_t)l * 65536 + (size_t)g * 1024;
        const float* w = W + (size_t)l * 10240;
        for (int k = t; k < 1024; k += 256) {
            float pv = p[k];
#pragma unroll
            for (int o = 0; o < 10; ++o) part[o] += pv * w[k * 10 + o];
        }
    }
    __shared__ float red[4][10];
#pragma unroll
    for (int o = 0; o < 10; ++o) {
        float v = part[o];
        for (int off = 32; off; off >>= 1) v += __shfl_down(v, off, 64);
        if ((t & 63) == 0) red[t >> 6][o] = v;
    }
    __syncthreads();
    if (t < 10) {
        float s = b0[t] + red[0][t] + red[1][t] + red[2][t] + red[3][t];
#pragma unroll
        for (int l = 0; l < 4; ++l) s += bb[l * 10 + t];
        out[g * 10 + t] = s;
    }
}

// ---------------------------------------------------------------------------
// host orchestration
// ---------------------------------------------------------------------------
static void launch_gemm(const unsigned short* A, const unsigned short* Bt,
                        int M, int N, int K, unsigned short* Cb,
                        int ostride, int ooff, const float* scalep, float* statp,
                        hipStream_t s) {
    if (M % 128 == 0 && M >= 8192)
        gemm_bf16<128><<<dim3(M / 128, N / 128), 256, 0, s>>>(A, Bt, M, N, K, Cb, ostride, ooff, scalep, statp);
    else
        gemm_bf16<64><<<dim3(M / 64, N / 128), 256, 0, s>>>(A, Bt, M, N, K, Cb, ostride, ooff, scalep, statp);
}

extern "C" void kernel_launch(void* const* d_in, const int* in_sizes, int n_in,
                              void* d_out, int out_size, void* d_ws, size_t ws_size,
                              hipStream_t stream) {
    const float* x1    = (const float*)d_in[0];
    const float* x2    = (const float*)d_in[1];
    const float* motif = (const float*)d_in[2];
    const int*   edge1 = (const int*)d_in[3];
    const int*   edge2 = (const int*)d_in[4];
    const int*   gid   = (const int*)d_in[5];
    const float* epsv  = (const float*)d_in[6];
    const float* atts  = (const float*)d_in[7];
    const float* m1W10 = (const float*)d_in[8];
    const float* m1W1r = (const float*)d_in[9];
    const float* m1bng = (const float*)d_in[11];
    const float* m1bnb = (const float*)d_in[12];
    const float* m1W2  = (const float*)d_in[13];
    const float* bn1g  = (const float*)d_in[15];
    const float* bn1b  = (const float*)d_in[16];
    const float* m2W10 = (const float*)d_in[17];
    const float* m2W1r = (const float*)d_in[18];
    const float* m2bng = (const float*)d_in[20];
    const float* m2bnb = (const float*)d_in[21];
    const float* m2W2  = (const float*)d_in[22];
    const float* bn2g  = (const float*)d_in[24];
    const float* bn2b  = (const float*)d_in[25];
    const float* pW0   = (const float*)d_in[26];
    const float* pb0   = (const float*)d_in[27];
    const float* pW    = (const float*)d_in[28];
    const float* pb    = (const float*)d_in[29];
    float* out = (float*)d_out;

    constexpr int N1 = 8192, N2 = 4096, E1 = 262144, E2 = 65536;

    char* base = (char*)d_ws;
    size_t off = 0;
    auto alloc = [&](size_t bytes) -> void* {
        void* p = base + off;
        off = (off + bytes + 255) & ~(size_t)255;
        return p;
    };

    // bf16 buffers
    unsigned short* motifT  = (unsigned short*)alloc((size_t)8192 * 4096 * 2);
    unsigned short* w1t1_0  = (unsigned short*)alloc((size_t)512 * 128 * 2);
    unsigned short* w1t1_r  = (unsigned short*)alloc((size_t)3 * 512 * 1024 * 2);
    unsigned short* w2t1    = (unsigned short*)alloc((size_t)4 * 512 * 512 * 2);
    unsigned short* w1t2_0  = (unsigned short*)alloc((size_t)512 * 64 * 2);
    unsigned short* w1t2_r  = (unsigned short*)alloc((size_t)3 * 512 * 512 * 2);
    unsigned short* w2t2    = (unsigned short*)alloc((size_t)4 * 512 * 512 * 2);
    unsigned short* x1b     = (unsigned short*)alloc((size_t)N1 * 128 * 2);
    unsigned short* x2b     = (unsigned short*)alloc((size_t)N2 * 64 * 2);
    unsigned short* H1b     = (unsigned short*)alloc((size_t)N1 * 1024 * 2);
    unsigned short* H2b     = (unsigned short*)alloc((size_t)N2 * 512 * 2);
    unsigned short* H2t     = (unsigned short*)alloc((size_t)512 * 4096 * 2);
    unsigned short* U1b     = (unsigned short*)alloc((size_t)N1 * 512 * 2);
    unsigned short* U2b     = (unsigned short*)alloc((size_t)N2 * 512 * 2);
    unsigned short* Y1b     = (unsigned short*)alloc((size_t)N1 * 512 * 2);
    unsigned short* T1b     = (unsigned short*)alloc((size_t)N1 * 512 * 2);
    unsigned short* Y2b     = (unsigned short*)alloc((size_t)N2 * 512 * 2);
    unsigned short* T2b     = (unsigned short*)alloc((size_t)N2 * 512 * 2);
    // memset-together region: cnt1 | cnt2 | ss
    int*   cnt1 = (int*)alloc((size_t)N1 * 4);
    int*   cnt2 = (int*)alloc((size_t)N2 * 4);
    float* ss   = (float*)alloc((size_t)16 * 1024 * 4);
    int*   offs1 = (int*)alloc((size_t)(N1 + 1) * 4);
    int*   offs2 = (int*)alloc((size_t)(N2 + 1) * 4);
    int*   cur1  = (int*)alloc((size_t)N1 * 4);
    int*   cur2  = (int*)alloc((size_t)N2 * 4);
    int*   srcs1 = (int*)alloc((size_t)E1 * 4);
    int*   srcs2 = (int*)alloc((size_t)E2 * 4);
    float* P0    = (float*)alloc((size_t)64 * 128 * 4);
    float* PL    = (float*)alloc((size_t)4 * 64 * 1024 * 4);
    float* aDev  = (float*)alloc(256);

    if (off > ws_size) return;

    // ---- setup ----
    hipMemsetAsync(cnt1, 0, (size_t)(N1 + N2) * 4 + 16 * 1024 * 4, stream);
    softmax2<<<1, 64, 0, stream>>>(atts, aDev);
    cvt_bf16<<<512, 256, 0, stream>>>((const f32x4*)x1, (u16x4*)x1b, N1 * 128 / 4);
    cvt_bf16<<<256, 256, 0, stream>>>((const f32x4*)x2, (u16x4*)x2b, N2 * 64 / 4);
    motif_transpose<<<dim3(128, 64), 256, 0, stream>>>(motif, motifT);
    transpose_cvt_b<<<dim3(16, 4, 1), dim3(32, 8), 0, stream>>>(m1W10, w1t1_0, 128, 512, 0, 0);
    transpose_cvt_b<<<dim3(16, 32, 3), dim3(32, 8), 0, stream>>>(m1W1r, w1t1_r, 1024, 512,
                                                                 (size_t)1024 * 512, (size_t)512 * 1024);
    transpose_cvt_b<<<dim3(16, 2, 1), dim3(32, 8), 0, stream>>>(m2W10, w1t2_0, 64, 512, 0, 0);
    transpose_cvt11<<<dim3(16, 16, 11), dim3(32, 8), 0, stream>>>(m1W2, w2t1, m2W1r, w1t2_r, m2W2, w2t2);
    csr_count2<<<(E1 + E2) / 256, 256, 0, stream>>>(edge1, E1, cnt1, edge2, E2, cnt2);
    csr_scan2<<<2, 1024, 0, stream>>>(cnt1, N1, offs1, cur1, cnt2, N2, offs2, cur2);
    csr_fill2<<<(E1 + E2) / 256, 256, 0, stream>>>(edge1, E1, cur1, srcs1, edge2, E2, cur2, srcs2);
    pool_f32<<<64, 128, 0, stream>>>(x1, 128, gid, N1, P0);

    // ---- layers ----
    for (int l = 0; l < 4; ++l) {
        float* ssl = ss + (size_t)l * 4096;   // 4 slots of 1024 per layer
        // branch 1 (base graph, M = 8192)
        launch_gemm(l ? H1b : x1b,
                    l ? w1t1_r + (size_t)(l - 1) * 512 * 1024 : w1t1_0,
                    N1, 512, l ? 1024 : 128, Y1b, 512, 0, nullptr, nullptr, stream);
        gather_stats<<<256, 128, 0, stream>>>((const u16x4*)Y1b, offs1, srcs1, epsv, l,
                                              (u16x4*)T1b, ssl + 0 * 1024, 32);
        bn_apply<<<64, 128, 0, stream>>>((const u16x4*)T1b, N1, ssl + 0 * 1024,
                                         m1bng + l * 512, m1bnb + l * 512, U1b, 512, 0, nullptr);
        launch_gemm(U1b, w2t1 + (size_t)l * 512 * 512, N1, 512, 512,
                    Y1b, 512, 0, nullptr, ssl + 1 * 1024, stream);
        bn_apply<<<64, 128, 0, stream>>>((const u16x4*)Y1b, N1, ssl + 1 * 1024,
                                         bn1g + l * 512, bn1b + l * 512, H1b, 1024, 0, aDev + 0);
        // branch 2 (hyper graph, M = 4096)
        launch_gemm(l ? H2b : x2b,
                    l ? w1t2_r + (size_t)(l - 1) * 512 * 512 : w1t2_0,
                    N2, 512, l ? 512 : 64, Y2b, 512, 0, nullptr, nullptr, stream);
        gather_stats<<<256, 128, 0, stream>>>((const u16x4*)Y2b, offs2, srcs2, epsv, l,
                                              (u16x4*)T2b, ssl + 2 * 1024, 16);
        bn_apply<<<32, 128, 0, stream>>>((const u16x4*)T2b, N2, ssl + 2 * 1024,
                                         m2bng + l * 512, m2bnb + l * 512, U2b, 512, 0, nullptr);
        launch_gemm(U2b, w2t2 + (size_t)l * 512 * 512, N2, 512, 512,
                    Y2b, 512, 0, nullptr, ssl + 3 * 1024, stream);
        bn_apply<<<32, 128, 0, stream>>>((const u16x4*)Y2b, N2, ssl + 3 * 1024,
                                         bn2g + l * 512, bn2b + l * 512, H2b, 512, 0, nullptr);
        // fusion: h2A = motif2A^T @ h2, epilogue writes concat half with a1
        transpose_bf16<<<dim3(16, 128), dim3(32, 8), 0, stream>>>(H2b, H2t, N2, 512);
        launch_gemm(motifT, H2t, N1, 512, 4096, H1b, 1024, 512, aDev + 1, nullptr, stream);
        // jumping-knowledge pooling of hidden[l+1]
        pool_bf16<<<64, 256, 0, stream>>>((const u16x4*)H1b, gid, N1, PL + (size_t)l * 64 * 1024);
    }

    score_kernel<<<64, 256, 0, stream>>>(P0, PL, pW0, pb0, pW, pb, out);
}

// Round 4
// 1896.694 us; speedup vs baseline: 1.5432x; 1.5432x over previous
//
#include <hip/hip_runtime.h>

// ---------------------------------------------------------------------------
// types & helpers
// ---------------------------------------------------------------------------
using bf16x8 = __attribute__((ext_vector_type(8))) short;
using f32x4  = __attribute__((ext_vector_type(4))) float;
using u16x4  = __attribute__((ext_vector_type(4))) unsigned short;
using as3_void  = __attribute__((address_space(3))) void;
using as1_cvoid = const __attribute__((address_space(1))) void;

__device__ __forceinline__ unsigned short f2bf(float x) {
    union { float f; unsigned u; } v; v.f = x;
    unsigned r = v.u + 0x7FFFu + ((v.u >> 16) & 1u);   // RNE
    return (unsigned short)(r >> 16);
}
__device__ __forceinline__ float bf2f(unsigned short h) {
    union { unsigned u; float f; } v; v.u = ((unsigned)h) << 16;
    return v.f;
}

// ---------------------------------------------------------------------------
// bf16 MFMA GEMM: Cb[M,N](bf16) = A[M,K](bf16 rm) @ Bt[N,K]^T (bf16) * scale
// BM x 128 tile, BK=64, 4 waves (2 row x 2 col). BM=128 -> m97 structure.
// Optional fused BN stats: column sum/sumsq atomicAdd into statp.
// LDS XOR-swizzle on the GLOBAL source (global_load_lds needs linear dest).
// ---------------------------------------------------------------------------
template<int BM>
__global__ __launch_bounds__(256) void gemm_bf16(
    const unsigned short* __restrict__ A, const unsigned short* __restrict__ Bt,
    int M, int N, int K,
    unsigned short* __restrict__ Cb, int ostride, int ooff,
    const float* __restrict__ scalep, float* __restrict__ statp)
{
    constexpr int WROWS = BM / 2;        // rows per row-wave
    constexpr int MI = WROWS / 16;       // i-fragments
    __shared__ __align__(16) unsigned short As[BM * 64];
    __shared__ __align__(16) unsigned short Bs[128 * 64];
    const int tid  = threadIdx.x;
    const int lane = tid & 63, wave = tid >> 6;
    const int m0 = blockIdx.x * BM, n0 = blockIdx.y * 128;
    const int wr = wave >> 1, wc = wave & 1;
    const int rl = lane & 15, kg = lane >> 4;
    f32x4 acc[MI][4] = {};

    for (int kt = 0; kt < K; kt += 64) {
#pragma unroll
        for (int it = 0; it < BM / 32; ++it) {           // A: BM*8 chunks
            int slot = it * 256 + tid;
            int r = slot >> 3, c = slot & 7;
            int cg = c ^ (r & 7);
            const unsigned short* ga = A + (size_t)(m0 + r) * K + (kt + cg * 8);
            __builtin_amdgcn_global_load_lds((as1_cvoid*)ga, (as3_void*)(As + slot * 8), 16, 0, 0);
        }
#pragma unroll
        for (int it = 0; it < 4; ++it) {                 // B: 1024 chunks
            int slot = it * 256 + tid;
            int r = slot >> 3, c = slot & 7;
            int cg = c ^ (r & 7);
            const unsigned short* gb = Bt + (size_t)(n0 + r) * K + (kt + cg * 8);
            __builtin_amdgcn_global_load_lds((as1_cvoid*)gb, (as3_void*)(Bs + slot * 8), 16, 0, 0);
        }
        __syncthreads();
#pragma unroll
        for (int kh = 0; kh < 2; ++kh) {
            bf16x8 a_[MI], b_[4];
#pragma unroll
            for (int i = 0; i < MI; ++i) {
                int ra = wr * WROWS + i * 16 + rl;
                int ca = (kh * 4 + kg) ^ (ra & 7);
                a_[i] = *reinterpret_cast<const bf16x8*>(&As[ra * 64 + ca * 8]);
            }
#pragma unroll
            for (int j = 0; j < 4; ++j) {
                int rb = wc * 64 + j * 16 + rl;
                int cb = (kh * 4 + kg) ^ (rb & 7);
                b_[j] = *reinterpret_cast<const bf16x8*>(&Bs[rb * 64 + cb * 8]);
            }
#pragma unroll
            for (int i = 0; i < MI; ++i)
#pragma unroll
                for (int j = 0; j < 4; ++j)
                    acc[i][j] = __builtin_amdgcn_mfma_f32_16x16x32_bf16(a_[i], b_[j], acc[i][j], 0, 0, 0);
        }
        __syncthreads();
    }

    const float sc = scalep ? *scalep : 1.0f;
#pragma unroll
    for (int i = 0; i < MI; ++i)
#pragma unroll
        for (int j = 0; j < 4; ++j)
#pragma unroll
            for (int e = 0; e < 4; ++e) {
                int rr = m0 + wr * WROWS + i * 16 + kg * 4 + e;
                int cc = n0 + wc * 64 + j * 16 + rl;
                Cb[(size_t)rr * ostride + ooff + cc] = f2bf(acc[i][j][e] * sc);
            }
    if (statp) {
#pragma unroll
        for (int j = 0; j < 4; ++j) {
            float s = 0.f, q = 0.f;
#pragma unroll
            for (int i = 0; i < MI; ++i)
#pragma unroll
                for (int e = 0; e < 4; ++e) {
                    float x = acc[i][j][e] * sc;
                    s += x; q += x * x;
                }
            s += __shfl_xor(s, 16); s += __shfl_xor(s, 32);
            q += __shfl_xor(q, 16); q += __shfl_xor(q, 32);
            if (kg == 0) {
                int cc = n0 + wc * 64 + j * 16 + rl;
                atomicAdd(&statp[cc], s);
                atomicAdd(&statp[512 + cc], q);
            }
        }
    }
}

// ---------------------------------------------------------------------------
// CSR build (both edge lists in one pass each)
// ---------------------------------------------------------------------------
__global__ void csr_count2(const int* __restrict__ e1, int E1, int* __restrict__ c1,
                           const int* __restrict__ e2, int E2, int* __restrict__ c2) {
    int i = blockIdx.x * 256 + threadIdx.x;
    if (i < E1) atomicAdd(&c1[e1[i]], 1);
    else if (i < E1 + E2) atomicAdd(&c2[e2[i - E1]], 1);
}

__global__ void csr_scan2(const int* __restrict__ cnt1, int n1, int* __restrict__ offs1, int* __restrict__ cur1,
                          const int* __restrict__ cnt2, int n2, int* __restrict__ offs2, int* __restrict__ cur2) {
    const int* cnt = blockIdx.x ? cnt2 : cnt1;
    int n           = blockIdx.x ? n2 : n1;
    int* offs       = blockIdx.x ? offs2 : offs1;
    int* cursor     = blockIdx.x ? cur2 : cur1;
    __shared__ int part[1024];
    int t = threadIdx.x;
    int per = n >> 10;
    int base = t * per;
    int loc[8];
    int s = 0;
    for (int j = 0; j < per; ++j) { loc[j] = s; s += cnt[base + j]; }
    part[t] = s;
    __syncthreads();
    for (int o = 1; o < 1024; o <<= 1) {
        int v = (t >= o) ? part[t - o] : 0;
        __syncthreads();
        part[t] += v;
        __syncthreads();
    }
    int excl = (t == 0) ? 0 : part[t - 1];
    for (int j = 0; j < per; ++j) {
        int v = excl + loc[j];
        offs[base + j] = v;
        cursor[base + j] = v;
    }
    if (t == 1023) offs[n] = part[1023];
}

__global__ void csr_fill2(const int* __restrict__ e1, int E1, int* __restrict__ cur1, int* __restrict__ s1,
                          const int* __restrict__ e2, int E2, int* __restrict__ cur2, int* __restrict__ s2) {
    int i = blockIdx.x * 256 + threadIdx.x;
    if (i < E1) {
        int d = e1[i], s = e1[E1 + i];
        s1[atomicAdd(&cur1[d], 1)] = s;
    } else if (i < E1 + E2) {
        int e = i - E1;
        int d = e2[e], s = e2[E2 + e];
        s2[atomicAdd(&cur2[d], 1)] = s;
    }
}

// ---------------------------------------------------------------------------
// gather, bf16 in/out (512 cols): one block per destination row, 128 thr x4.
// T[i,:] = sum_{e in in(i)} Y[src_e,:] + (1+eps[l]) * Y[i,:]
// 4-way unrolled independent accumulators for load-level parallelism.
// ---------------------------------------------------------------------------
__global__ __launch_bounds__(128) void gather_bf16(
    const u16x4* __restrict__ Y, const int* __restrict__ offs,
    const int* __restrict__ srcs, const float* __restrict__ epsv,
    int l, u16x4* __restrict__ T)
{
    int i = blockIdx.x;
    int c = threadIdx.x;
    float e = 1.0f + epsv[l];
    int lo = offs[i], hi = offs[i + 1];
    u16x4 hv = Y[(size_t)i * 128 + c];
    f32x4 a0, a1 = {}, a2 = {}, a3 = {};
#pragma unroll
    for (int j = 0; j < 4; ++j) a0[j] = e * bf2f(hv[j]);
    int k = lo;
    for (; k + 4 <= hi; k += 4) {
        int s0 = srcs[k], s1 = srcs[k + 1], s2 = srcs[k + 2], s3 = srcs[k + 3];
        u16x4 v0 = Y[(size_t)s0 * 128 + c];
        u16x4 v1 = Y[(size_t)s1 * 128 + c];
        u16x4 v2 = Y[(size_t)s2 * 128 + c];
        u16x4 v3 = Y[(size_t)s3 * 128 + c];
#pragma unroll
        for (int j = 0; j < 4; ++j) {
            a0[j] += bf2f(v0[j]); a1[j] += bf2f(v1[j]);
            a2[j] += bf2f(v2[j]); a3[j] += bf2f(v3[j]);
        }
    }
    for (; k < hi; ++k) {
        u16x4 v = Y[(size_t)srcs[k] * 128 + c];
#pragma unroll
        for (int j = 0; j < 4; ++j) a0[j] += bf2f(v[j]);
    }
    f32x4 acc = (a0 + a1) + (a2 + a3);
    u16x4 o;
#pragma unroll
    for (int j = 0; j < 4; ++j) o[j] = f2bf(acc[j]);
    T[(size_t)i * 128 + c] = o;
}

// column sum/sumsq over bf16 [M][512] -> ss[0..511], ss[512..1023]
__global__ void bn_stats_bf16(const u16x4* __restrict__ X, int M, float* __restrict__ ss) {
    int c = threadIdx.x;                                // 128 threads x 4 cols
    int rows = M / gridDim.x;
    int r0 = blockIdx.x * rows;
    f32x4 s = {}, q = {};
    for (int r = 0; r < rows; ++r) {
        u16x4 v = X[(size_t)(r0 + r) * 128 + c];
        f32x4 f;
#pragma unroll
        for (int j = 0; j < 4; ++j) f[j] = bf2f(v[j]);
        s += f; q += f * f;
    }
#pragma unroll
    for (int j = 0; j < 4; ++j) {
        atomicAdd(&ss[c * 4 + j], s[j]);
        atomicAdd(&ss[512 + c * 4 + j], q[j]);
    }
}

// bn finalize+apply+ReLU, bf16 in -> bf16 out (strided, optional scale)
__global__ void bn_apply(const u16x4* __restrict__ X, int M, const float* __restrict__ ss,
                         const float* __restrict__ g, const float* __restrict__ b,
                         unsigned short* __restrict__ out, int ostride, int ooff,
                         const float* __restrict__ scale) {
    int c = threadIdx.x;                                // 128 threads x 4 cols
    float inv = 1.0f / (float)M;
    float al[4], be[4];
#pragma unroll
    for (int i = 0; i < 4; ++i) {
        float mean = ss[c * 4 + i] * inv;
        float var  = ss[512 + c * 4 + i] * inv - mean * mean;
        al[i] = g[c * 4 + i] * rsqrtf(var + 1e-5f);
        be[i] = b[c * 4 + i] - mean * al[i];
    }
    float sc = scale ? *scale : 1.0f;
    int rows = M / gridDim.x;
    int r0 = blockIdx.x * rows;
    for (int r = 0; r < rows; ++r) {
        u16x4 v = X[(size_t)(r0 + r) * 128 + c];
        u16x4 h;
#pragma unroll
        for (int i = 0; i < 4; ++i)
            h[i] = f2bf(fmaxf(al[i] * bf2f(v[i]) + be[i], 0.f) * sc);
        *reinterpret_cast<u16x4*>(out + (size_t)(r0 + r) * ostride + ooff + c * 4) = h;
    }
}

// contiguous f32 -> bf16 convert
__global__ void cvt_bf16(const f32x4* __restrict__ X, u16x4* __restrict__ out, int n4) {
    for (int i = blockIdx.x * blockDim.x + threadIdx.x; i < n4; i += gridDim.x * blockDim.x) {
        f32x4 v = X[i];
        u16x4 h;
#pragma unroll
        for (int j = 0; j < 4; ++j) h[j] = f2bf(v[j]);
        out[i] = h;
    }
}

// ---------------------------------------------------------------------------
// motif transpose: S f32 [4096][8192] -> D bf16 [8192][4096], 64x64 tiles
// ---------------------------------------------------------------------------
__global__ __launch_bounds__(256) void motif_transpose(const float* __restrict__ S,
                                                       unsigned short* __restrict__ D) {
    __shared__ unsigned short tile[64][66];
    int m0 = blockIdx.x * 64;   // source col block (8192 dim)
    int k0 = blockIdx.y * 64;   // source row block (4096 dim)
    int t = threadIdx.x;
    int r = t >> 4, cq = t & 15;
#pragma unroll
    for (int p = 0; p < 4; ++p) {
        int row = r + p * 16;
        f32x4 v = *reinterpret_cast<const f32x4*>(S + (size_t)(k0 + row) * 8192 + m0 + cq * 4);
        u16x4 h;
#pragma unroll
        for (int j = 0; j < 4; ++j) h[j] = f2bf(v[j]);
        *reinterpret_cast<u16x4*>(&tile[row][cq * 4]) = h;
    }
    __syncthreads();
#pragma unroll
    for (int p = 0; p < 4; ++p) {
        int col = r + p * 16;   // dest row = m0+col
        u16x4 h;
#pragma unroll
        for (int i = 0; i < 4; ++i) h[i] = tile[cq * 4 + i][col];
        *reinterpret_cast<u16x4*>(D + (size_t)(m0 + col) * 4096 + k0 + cq * 4) = h;
    }
}

// ---------------------------------------------------------------------------
// small transposes (weights), batched
// ---------------------------------------------------------------------------
__global__ void transpose_cvt_b(const float* __restrict__ S, unsigned short* __restrict__ D,
                                int rows, int cols, size_t sstride, size_t dstride) {
    S += blockIdx.z * sstride; D += blockIdx.z * dstride;
    __shared__ unsigned short tile[32][33];
    int x0 = blockIdx.x * 32, y0 = blockIdx.y * 32;
    for (int j = threadIdx.y; j < 32; j += blockDim.y)
        tile[j][threadIdx.x] = f2bf(S[(size_t)(y0 + j) * cols + x0 + threadIdx.x]);
    __syncthreads();
    for (int j = threadIdx.y; j < 32; j += blockDim.y)
        D[(size_t)(x0 + j) * rows + y0 + threadIdx.x] = tile[threadIdx.x][j];
}

// 11 square 512x512 weights in one launch: z<4 -> m1W2, z<7 -> m2W1r, else m2W2
__global__ void transpose_cvt11(const float* __restrict__ A, unsigned short* __restrict__ Ad,
                                const float* __restrict__ B, unsigned short* __restrict__ Bd,
                                const float* __restrict__ Cs, unsigned short* __restrict__ Cd) {
    int z = blockIdx.z;
    const float* S; unsigned short* D;
    if (z < 4)      { S = A  + (size_t)z * 262144;       D = Ad + (size_t)z * 262144; }
    else if (z < 7) { S = B  + (size_t)(z - 4) * 262144; D = Bd + (size_t)(z - 4) * 262144; }
    else            { S = Cs + (size_t)(z - 7) * 262144; D = Cd + (size_t)(z - 7) * 262144; }
    __shared__ unsigned short tile[32][33];
    int x0 = blockIdx.x * 32, y0 = blockIdx.y * 32;
    for (int j = threadIdx.y; j < 32; j += blockDim.y)
        tile[j][threadIdx.x] = f2bf(S[(size_t)(y0 + j) * 512 + x0 + threadIdx.x]);
    __syncthreads();
    for (int j = threadIdx.y; j < 32; j += blockDim.y)
        D[(size_t)(x0 + j) * 512 + y0 + threadIdx.x] = tile[threadIdx.x][j];
}

__global__ void transpose_bf16(const unsigned short* __restrict__ S, unsigned short* __restrict__ D,
                               int rows, int cols) { // D[c][r] = S[r][c]
    __shared__ unsigned short tile[32][33];
    int x0 = blockIdx.x * 32, y0 = blockIdx.y * 32;
    for (int j = threadIdx.y; j < 32; j += blockDim.y)
        tile[j][threadIdx.x] = S[(size_t)(y0 + j) * cols + x0 + threadIdx.x];
    __syncthreads();
    for (int j = threadIdx.y; j < 32; j += blockDim.y)
        D[(size_t)(x0 + j) * rows + y0 + threadIdx.x] = tile[threadIdx.x][j];
}

// ---------------------------------------------------------------------------
// graph pooling (graph_ids sorted -> binary-search row range per graph)
// ---------------------------------------------------------------------------
__device__ __forceinline__ int lbound(const int* __restrict__ a, int n, int v) {
    int lo = 0, hi = n;
    while (lo < hi) { int m = (lo + hi) >> 1; if (a[m] < v) lo = m + 1; else hi = m; }
    return lo;
}

__global__ void pool_bf16(const u16x4* __restrict__ Hm, const int* __restrict__ gid,
                          int n, float* __restrict__ P) {   // 1024 cols
    int g = blockIdx.x;
    int lo = lbound(gid, n, g), hi = lbound(gid, n, g + 1);
    int c = threadIdx.x;
    f32x4 s = {};
    for (int i = lo; i < hi; ++i) {
        u16x4 v = Hm[(size_t)i * 256 + c];
#pragma unroll
        for (int j = 0; j < 4; ++j) s[j] += bf2f(v[j]);
    }
#pragma unroll
    for (int j = 0; j < 4; ++j)
        P[(size_t)g * 1024 + c * 4 + j] = s[j];
}

__global__ void pool_f32(const float* __restrict__ Hm, int cols,
                         const int* __restrict__ gid, int n, float* __restrict__ P) {
    int g = blockIdx.x;
    int lo = lbound(gid, n, g), hi = lbound(gid, n, g + 1);
    for (int c = threadIdx.x; c < cols; c += blockDim.x) {
        float s = 0.f;
        for (int i = lo; i < hi; ++i) s += Hm[(size_t)i * cols + c];
        P[(size_t)g * cols + c] = s;
    }
}

__global__ void softmax2(const float* __restrict__ atts, float* __restrict__ a) {
    if (threadIdx.x == 0) {
        float m = fmaxf(atts[0], atts[1]);
        float e0 = expf(atts[0] - m), e1 = expf(atts[1] - m);
        float inv = 1.0f / (e0 + e1);
        a[0] = e0 * inv; a[1] = e1 * inv;
    }
}

// score[g,o] = P0[g]@W0 + b0 + sum_l PL[l][g]@W[l] + b[l]
__global__ __launch_bounds__(256) void score_kernel(
    const float* __restrict__ P0, const float* __restrict__ PL,
    const float* __restrict__ W0, const float* __restrict__ b0,
    const float* __restrict__ W, const float* __restrict__ bb,
    float* __restrict__ out)
{
    int g = blockIdx.x;
    int t = threadIdx.x;
    float part[10];
#pragma unroll
    for (int o = 0; o < 10; ++o) part[o] = 0.f;
    if (t < 128) {
        float p = P0[g * 128 + t];
#pragma unroll
        for (int o = 0; o < 10; ++o) part[o] += p * W0[t * 10 + o];
    }
    for (int l = 0; l < 4; ++l) {
        const float* p = PL + (size_t)l * 65536 + (size_t)g * 1024;
        const float* w = W + (size_t)l * 10240;
        for (int k = t; k < 1024; k += 256) {
            float pv = p[k];
#pragma unroll
            for (int o = 0; o < 10; ++o) part[o] += pv * w[k * 10 + o];
        }
    }
    __shared__ float red[4][10];
#pragma unroll
    for (int o = 0; o < 10; ++o) {
        float v = part[o];
        for (int off = 32; off; off >>= 1) v += __shfl_down(v, off, 64);
        if ((t & 63) == 0) red[t >> 6][o] = v;
    }
    __syncthreads();
    if (t < 10) {
        float s = b0[t] + red[0][t] + red[1][t] + red[2][t] + red[3][t];
#pragma unroll
        for (int l = 0; l < 4; ++l) s += bb[l * 10 + t];
        out[g * 10 + t] = s;
    }
}

// ---------------------------------------------------------------------------
// host orchestration
// ---------------------------------------------------------------------------
static void launch_gemm(const unsigned short* A, const unsigned short* Bt,
                        int M, int N, int K, unsigned short* Cb,
                        int ostride, int ooff, const float* scalep, float* statp,
                        hipStream_t s) {
    if (M % 128 == 0 && M >= 8192)
        gemm_bf16<128><<<dim3(M / 128, N / 128), 256, 0, s>>>(A, Bt, M, N, K, Cb, ostride, ooff, scalep, statp);
    else
        gemm_bf16<64><<<dim3(M / 64, N / 128), 256, 0, s>>>(A, Bt, M, N, K, Cb, ostride, ooff, scalep, statp);
}

extern "C" void kernel_launch(void* const* d_in, const int* in_sizes, int n_in,
                              void* d_out, int out_size, void* d_ws, size_t ws_size,
                              hipStream_t stream) {
    const float* x1    = (const float*)d_in[0];
    const float* x2    = (const float*)d_in[1];
    const float* motif = (const float*)d_in[2];
    const int*   edge1 = (const int*)d_in[3];
    const int*   edge2 = (const int*)d_in[4];
    const int*   gid   = (const int*)d_in[5];
    const float* epsv  = (const float*)d_in[6];
    const float* atts  = (const float*)d_in[7];
    const float* m1W10 = (const float*)d_in[8];
    const float* m1W1r = (const float*)d_in[9];
    const float* m1bng = (const float*)d_in[11];
    const float* m1bnb = (const float*)d_in[12];
    const float* m1W2  = (const float*)d_in[13];
    const float* bn1g  = (const float*)d_in[15];
    const float* bn1b  = (const float*)d_in[16];
    const float* m2W10 = (const float*)d_in[17];
    const float* m2W1r = (const float*)d_in[18];
    const float* m2bng = (const float*)d_in[20];
    const float* m2bnb = (const float*)d_in[21];
    const float* m2W2  = (const float*)d_in[22];
    const float* bn2g  = (const float*)d_in[24];
    const float* bn2b  = (const float*)d_in[25];
    const float* pW0   = (const float*)d_in[26];
    const float* pb0   = (const float*)d_in[27];
    const float* pW    = (const float*)d_in[28];
    const float* pb    = (const float*)d_in[29];
    float* out = (float*)d_out;

    constexpr int N1 = 8192, N2 = 4096, E1 = 262144, E2 = 65536;

    char* base = (char*)d_ws;
    size_t off = 0;
    auto alloc = [&](size_t bytes) -> void* {
        void* p = base + off;
        off = (off + bytes + 255) & ~(size_t)255;
        return p;
    };

    // bf16 buffers
    unsigned short* motifT  = (unsigned short*)alloc((size_t)8192 * 4096 * 2);
    unsigned short* w1t1_0  = (unsigned short*)alloc((size_t)512 * 128 * 2);
    unsigned short* w1t1_r  = (unsigned short*)alloc((size_t)3 * 512 * 1024 * 2);
    unsigned short* w2t1    = (unsigned short*)alloc((size_t)4 * 512 * 512 * 2);
    unsigned short* w1t2_0  = (unsigned short*)alloc((size_t)512 * 64 * 2);
    unsigned short* w1t2_r  = (unsigned short*)alloc((size_t)3 * 512 * 512 * 2);
    unsigned short* w2t2    = (unsigned short*)alloc((size_t)4 * 512 * 512 * 2);
    unsigned short* x1b     = (unsigned short*)alloc((size_t)N1 * 128 * 2);
    unsigned short* x2b     = (unsigned short*)alloc((size_t)N2 * 64 * 2);
    unsigned short* H1b     = (unsigned short*)alloc((size_t)N1 * 1024 * 2);
    unsigned short* H2b     = (unsigned short*)alloc((size_t)N2 * 512 * 2);
    unsigned short* H2t     = (unsigned short*)alloc((size_t)512 * 4096 * 2);
    unsigned short* U1b     = (unsigned short*)alloc((size_t)N1 * 512 * 2);
    unsigned short* U2b     = (unsigned short*)alloc((size_t)N2 * 512 * 2);
    unsigned short* Y1b     = (unsigned short*)alloc((size_t)N1 * 512 * 2);
    unsigned short* T1b     = (unsigned short*)alloc((size_t)N1 * 512 * 2);
    unsigned short* Y2b     = (unsigned short*)alloc((size_t)N2 * 512 * 2);
    unsigned short* T2b     = (unsigned short*)alloc((size_t)N2 * 512 * 2);
    // memset-together region: cnt1 | cnt2 | ss
    int*   cnt1 = (int*)alloc((size_t)N1 * 4);
    int*   cnt2 = (int*)alloc((size_t)N2 * 4);
    float* ss   = (float*)alloc((size_t)16 * 1024 * 4);
    int*   offs1 = (int*)alloc((size_t)(N1 + 1) * 4);
    int*   offs2 = (int*)alloc((size_t)(N2 + 1) * 4);
    int*   cur1  = (int*)alloc((size_t)N1 * 4);
    int*   cur2  = (int*)alloc((size_t)N2 * 4);
    int*   srcs1 = (int*)alloc((size_t)E1 * 4);
    int*   srcs2 = (int*)alloc((size_t)E2 * 4);
    float* P0    = (float*)alloc((size_t)64 * 128 * 4);
    float* PL    = (float*)alloc((size_t)4 * 64 * 1024 * 4);
    float* aDev  = (float*)alloc(256);

    if (off > ws_size) return;

    // ---- setup ----
    hipMemsetAsync(cnt1, 0, (size_t)(N1 + N2) * 4 + 16 * 1024 * 4, stream);
    softmax2<<<1, 64, 0, stream>>>(atts, aDev);
    cvt_bf16<<<512, 256, 0, stream>>>((const f32x4*)x1, (u16x4*)x1b, N1 * 128 / 4);
    cvt_bf16<<<256, 256, 0, stream>>>((const f32x4*)x2, (u16x4*)x2b, N2 * 64 / 4);
    motif_transpose<<<dim3(128, 64), 256, 0, stream>>>(motif, motifT);
    transpose_cvt_b<<<dim3(16, 4, 1), dim3(32, 8), 0, stream>>>(m1W10, w1t1_0, 128, 512, 0, 0);
    transpose_cvt_b<<<dim3(16, 32, 3), dim3(32, 8), 0, stream>>>(m1W1r, w1t1_r, 1024, 512,
                                                                 (size_t)1024 * 512, (size_t)512 * 1024);
    transpose_cvt_b<<<dim3(16, 2, 1), dim3(32, 8), 0, stream>>>(m2W10, w1t2_0, 64, 512, 0, 0);
    transpose_cvt11<<<dim3(16, 16, 11), dim3(32, 8), 0, stream>>>(m1W2, w2t1, m2W1r, w1t2_r, m2W2, w2t2);
    csr_count2<<<(E1 + E2) / 256, 256, 0, stream>>>(edge1, E1, cnt1, edge2, E2, cnt2);
    csr_scan2<<<2, 1024, 0, stream>>>(cnt1, N1, offs1, cur1, cnt2, N2, offs2, cur2);
    csr_fill2<<<(E1 + E2) / 256, 256, 0, stream>>>(edge1, E1, cur1, srcs1, edge2, E2, cur2, srcs2);
    pool_f32<<<64, 128, 0, stream>>>(x1, 128, gid, N1, P0);

    // ---- layers ----
    for (int l = 0; l < 4; ++l) {
        float* ssl = ss + (size_t)l * 4096;   // 4 slots of 1024 per layer
        // branch 1 (base graph, M = 8192)
        launch_gemm(l ? H1b : x1b,
                    l ? w1t1_r + (size_t)(l - 1) * 512 * 1024 : w1t1_0,
                    N1, 512, l ? 1024 : 128, Y1b, 512, 0, nullptr, nullptr, stream);
        gather_bf16<<<N1, 128, 0, stream>>>((const u16x4*)Y1b, offs1, srcs1, epsv, l, (u16x4*)T1b);
        bn_stats_bf16<<<64, 128, 0, stream>>>((const u16x4*)T1b, N1, ssl + 0 * 1024);
        bn_apply<<<64, 128, 0, stream>>>((const u16x4*)T1b, N1, ssl + 0 * 1024,
                                         m1bng + l * 512, m1bnb + l * 512, U1b, 512, 0, nullptr);
        launch_gemm(U1b, w2t1 + (size_t)l * 512 * 512, N1, 512, 512,
                    Y1b, 512, 0, nullptr, ssl + 1 * 1024, stream);
        bn_apply<<<64, 128, 0, stream>>>((const u16x4*)Y1b, N1, ssl + 1 * 1024,
                                         bn1g + l * 512, bn1b + l * 512, H1b, 1024, 0, aDev + 0);
        // branch 2 (hyper graph, M = 4096)
        launch_gemm(l ? H2b : x2b,
                    l ? w1t2_r + (size_t)(l - 1) * 512 * 512 : w1t2_0,
                    N2, 512, l ? 512 : 64, Y2b, 512, 0, nullptr, nullptr, stream);
        gather_bf16<<<N2, 128, 0, stream>>>((const u16x4*)Y2b, offs2, srcs2, epsv, l, (u16x4*)T2b);
        bn_stats_bf16<<<64, 128, 0, stream>>>((const u16x4*)T2b, N2, ssl + 2 * 1024);
        bn_apply<<<32, 128, 0, stream>>>((const u16x4*)T2b, N2, ssl + 2 * 1024,
                                         m2bng + l * 512, m2bnb + l * 512, U2b, 512, 0, nullptr);
        launch_gemm(U2b, w2t2 + (size_t)l * 512 * 512, N2, 512, 512,
                    Y2b, 512, 0, nullptr, ssl + 3 * 1024, stream);
        bn_apply<<<32, 128, 0, stream>>>((const u16x4*)Y2b, N2, ssl + 3 * 1024,
                                         bn2g + l * 512, bn2b + l * 512, H2b, 512, 0, nullptr);
        // fusion: h2A = motif2A^T @ h2, epilogue writes concat half with a1
        transpose_bf16<<<dim3(16, 128), dim3(32, 8), 0, stream>>>(H2b, H2t, N2, 512);
        launch_gemm(motifT, H2t, N1, 512, 4096, H1b, 1024, 512, aDev + 1, nullptr, stream);
        // jumping-knowledge pooling of hidden[l+1]
        pool_bf16<<<64, 256, 0, stream>>>((const u16x4*)H1b, gid, N1, PL + (size_t)l * 64 * 1024);
    }

    score_kernel<<<64, 256, 0, stream>>>(P0, PL, pW0, pb0, pW, pb, out);
}

// Round 5
// 1336.939 us; speedup vs baseline: 2.1893x; 1.4187x over previous
//
#include <hip/hip_runtime.h>

// ---------------------------------------------------------------------------
// types & helpers
// ---------------------------------------------------------------------------
using bf16x8 = __attribute__((ext_vector_type(8))) short;
using f32x4  = __attribute__((ext_vector_type(4))) float;
using u16x4  = __attribute__((ext_vector_type(4))) unsigned short;
using as3_void  = __attribute__((address_space(3))) void;
using as1_cvoid = const __attribute__((address_space(1))) void;

__device__ __forceinline__ unsigned short f2bf(float x) {
    union { float f; unsigned u; } v; v.f = x;
    unsigned r = v.u + 0x7FFFu + ((v.u >> 16) & 1u);   // RNE
    return (unsigned short)(r >> 16);
}
__device__ __forceinline__ float bf2f(unsigned short h) {
    union { unsigned u; float f; } v; v.u = ((unsigned)h) << 16;
    return v.f;
}

// ---------------------------------------------------------------------------
// bf16 MFMA GEMM: BM x 128 tile, BK=64, 4 waves (2x2).
// Modes: Cp != null -> split-K f32 partials (grid.z = KS, each z does K/KS);
//        else bf16 store * (*scalep or 1), optional fused BN stats (statp).
// LDS XOR-swizzle applied on the GLOBAL source (global_load_lds linear dest).
// ---------------------------------------------------------------------------
template<int BM>
__global__ __launch_bounds__(256) void gemm_bf16(
    const unsigned short* __restrict__ A, const unsigned short* __restrict__ Bt,
    int M, int N, int K,
    unsigned short* __restrict__ Cb, int ostride, int ooff,
    const float* __restrict__ scalep, float* __restrict__ statp,
    float* __restrict__ Cp)
{
    constexpr int WROWS = BM / 2;        // rows per row-wave
    constexpr int MI = WROWS / 16;       // i-fragments
    __shared__ __align__(16) unsigned short As[BM * 64];
    __shared__ __align__(16) unsigned short Bs[128 * 64];
    const int tid  = threadIdx.x;
    const int lane = tid & 63, wave = tid >> 6;
    const int m0 = blockIdx.x * BM, n0 = blockIdx.y * 128;
    const int wr = wave >> 1, wc = wave & 1;
    const int rl = lane & 15, kg = lane >> 4;
    f32x4 acc[MI][4] = {};

    const int kn   = K / gridDim.z;
    const int kbeg = blockIdx.z * kn;

    for (int kt = kbeg; kt < kbeg + kn; kt += 64) {
#pragma unroll
        for (int it = 0; it < BM / 32; ++it) {           // A: BM*8 chunks
            int slot = it * 256 + tid;
            int r = slot >> 3, c = slot & 7;
            int cg = c ^ (r & 7);
            const unsigned short* ga = A + (size_t)(m0 + r) * K + (kt + cg * 8);
            __builtin_amdgcn_global_load_lds((as1_cvoid*)ga, (as3_void*)(As + slot * 8), 16, 0, 0);
        }
#pragma unroll
        for (int it = 0; it < 4; ++it) {                 // B: 1024 chunks
            int slot = it * 256 + tid;
            int r = slot >> 3, c = slot & 7;
            int cg = c ^ (r & 7);
            const unsigned short* gb = Bt + (size_t)(n0 + r) * K + (kt + cg * 8);
            __builtin_amdgcn_global_load_lds((as1_cvoid*)gb, (as3_void*)(Bs + slot * 8), 16, 0, 0);
        }
        __syncthreads();
#pragma unroll
        for (int kh = 0; kh < 2; ++kh) {
            bf16x8 a_[MI], b_[4];
#pragma unroll
            for (int i = 0; i < MI; ++i) {
                int ra = wr * WROWS + i * 16 + rl;
                int ca = (kh * 4 + kg) ^ (ra & 7);
                a_[i] = *reinterpret_cast<const bf16x8*>(&As[ra * 64 + ca * 8]);
            }
#pragma unroll
            for (int j = 0; j < 4; ++j) {
                int rb = wc * 64 + j * 16 + rl;
                int cb = (kh * 4 + kg) ^ (rb & 7);
                b_[j] = *reinterpret_cast<const bf16x8*>(&Bs[rb * 64 + cb * 8]);
            }
#pragma unroll
            for (int i = 0; i < MI; ++i)
#pragma unroll
                for (int j = 0; j < 4; ++j)
                    acc[i][j] = __builtin_amdgcn_mfma_f32_16x16x32_bf16(a_[i], b_[j], acc[i][j], 0, 0, 0);
        }
        __syncthreads();
    }

    if (Cp) {                                            // split-K partials
        float* dst = Cp + (size_t)blockIdx.z * M * N;
#pragma unroll
        for (int i = 0; i < MI; ++i)
#pragma unroll
            for (int j = 0; j < 4; ++j)
#pragma unroll
                for (int e = 0; e < 4; ++e) {
                    int rr = m0 + wr * WROWS + i * 16 + kg * 4 + e;
                    int cc = n0 + wc * 64 + j * 16 + rl;
                    dst[(size_t)rr * N + cc] = acc[i][j][e];
                }
        return;
    }

    const float sc = scalep ? *scalep : 1.0f;
#pragma unroll
    for (int i = 0; i < MI; ++i)
#pragma unroll
        for (int j = 0; j < 4; ++j)
#pragma unroll
            for (int e = 0; e < 4; ++e) {
                int rr = m0 + wr * WROWS + i * 16 + kg * 4 + e;
                int cc = n0 + wc * 64 + j * 16 + rl;
                Cb[(size_t)rr * ostride + ooff + cc] = f2bf(acc[i][j][e] * sc);
            }
    if (statp) {
#pragma unroll
        for (int j = 0; j < 4; ++j) {
            float s = 0.f, q = 0.f;
#pragma unroll
            for (int i = 0; i < MI; ++i)
#pragma unroll
                for (int e = 0; e < 4; ++e) {
                    float x = acc[i][j][e] * sc;
                    s += x; q += x * x;
                }
            s += __shfl_xor(s, 16); s += __shfl_xor(s, 32);
            q += __shfl_xor(q, 16); q += __shfl_xor(q, 32);
            if (kg == 0) {
                int cc = n0 + wc * 64 + j * 16 + rl;
                atomicAdd(&statp[cc], s);
                atomicAdd(&statp[512 + cc], q);
            }
        }
    }
}

// sum KS split-K partials (8192x512), scale, cvt bf16, strided store
__global__ __launch_bounds__(256) void sumk_cvt(
    const f32x4* __restrict__ P, int ks, const float* __restrict__ scalep,
    unsigned short* __restrict__ out, int ostride, int ooff)
{
    const int total = 8192 * 128;
    float sc = *scalep;
    for (int i = blockIdx.x * 256 + threadIdx.x; i < total; i += gridDim.x * 256) {
        f32x4 s = P[i];
        for (int z = 1; z < ks; ++z) s += P[(size_t)z * total + i];
        int r = i >> 7, c = i & 127;
        u16x4 h;
#pragma unroll
        for (int j = 0; j < 4; ++j) h[j] = f2bf(s[j] * sc);
        *reinterpret_cast<u16x4*>(out + (size_t)r * ostride + ooff + c * 4) = h;
    }
}

// ---------------------------------------------------------------------------
// CSR build (both edge lists in one pass each)
// ---------------------------------------------------------------------------
__global__ void csr_count2(const int* __restrict__ e1, int E1, int* __restrict__ c1,
                           const int* __restrict__ e2, int E2, int* __restrict__ c2) {
    int i = blockIdx.x * 256 + threadIdx.x;
    if (i < E1) atomicAdd(&c1[e1[i]], 1);
    else if (i < E1 + E2) atomicAdd(&c2[e2[i - E1]], 1);
}

__global__ void csr_scan2(const int* __restrict__ cnt1, int n1, int* __restrict__ offs1, int* __restrict__ cur1,
                          const int* __restrict__ cnt2, int n2, int* __restrict__ offs2, int* __restrict__ cur2) {
    const int* cnt = blockIdx.x ? cnt2 : cnt1;
    int n           = blockIdx.x ? n2 : n1;
    int* offs       = blockIdx.x ? offs2 : offs1;
    int* cursor     = blockIdx.x ? cur2 : cur1;
    __shared__ int part[1024];
    int t = threadIdx.x;
    int per = n >> 10;
    int base = t * per;
    int loc[8];
    int s = 0;
    for (int j = 0; j < per; ++j) { loc[j] = s; s += cnt[base + j]; }
    part[t] = s;
    __syncthreads();
    for (int o = 1; o < 1024; o <<= 1) {
        int v = (t >= o) ? part[t - o] : 0;
        __syncthreads();
        part[t] += v;
        __syncthreads();
    }
    int excl = (t == 0) ? 0 : part[t - 1];
    for (int j = 0; j < per; ++j) {
        int v = excl + loc[j];
        offs[base + j] = v;
        cursor[base + j] = v;
    }
    if (t == 1023) offs[n] = part[1023];
}

__global__ void csr_fill2(const int* __restrict__ e1, int E1, int* __restrict__ cur1, int* __restrict__ s1,
                          const int* __restrict__ e2, int E2, int* __restrict__ cur2, int* __restrict__ s2) {
    int i = blockIdx.x * 256 + threadIdx.x;
    if (i < E1) {
        int d = e1[i], s = e1[E1 + i];
        s1[atomicAdd(&cur1[d], 1)] = s;
    } else if (i < E1 + E2) {
        int e = i - E1;
        int d = e2[e], s = e2[E2 + e];
        s2[atomicAdd(&cur2[d], 1)] = s;
    }
}

// ---------------------------------------------------------------------------
// gather for BOTH branches in one dispatch: block < n1 -> branch1, else 2.
// T[i,:] = sum_{e in in(i)} Y[src_e,:] + (1+eps[l]) * Y[i,:]  (512 cols)
// ---------------------------------------------------------------------------
__global__ __launch_bounds__(128) void gather2_bf16(
    const u16x4* __restrict__ Y1, const int* __restrict__ offs1, const int* __restrict__ srcs1,
    u16x4* __restrict__ T1, int n1,
    const u16x4* __restrict__ Y2, const int* __restrict__ offs2, const int* __restrict__ srcs2,
    u16x4* __restrict__ T2,
    const float* __restrict__ epsv, int l)
{
    int i = blockIdx.x;
    const u16x4* Y; u16x4* T; const int *offs, *srcs;
    if (i < n1) { Y = Y1; T = T1; offs = offs1; srcs = srcs1; }
    else        { i -= n1; Y = Y2; T = T2; offs = offs2; srcs = srcs2; }
    int c = threadIdx.x;
    float e = 1.0f + epsv[l];
    int lo = offs[i], hi = offs[i + 1];
    u16x4 hv = Y[(size_t)i * 128 + c];
    f32x4 a0, a1 = {}, a2 = {}, a3 = {};
#pragma unroll
    for (int j = 0; j < 4; ++j) a0[j] = e * bf2f(hv[j]);
    int k = lo;
    for (; k + 4 <= hi; k += 4) {
        int s0 = srcs[k], s1 = srcs[k + 1], s2 = srcs[k + 2], s3 = srcs[k + 3];
        u16x4 v0 = Y[(size_t)s0 * 128 + c];
        u16x4 v1 = Y[(size_t)s1 * 128 + c];
        u16x4 v2 = Y[(size_t)s2 * 128 + c];
        u16x4 v3 = Y[(size_t)s3 * 128 + c];
#pragma unroll
        for (int j = 0; j < 4; ++j) {
            a0[j] += bf2f(v0[j]); a1[j] += bf2f(v1[j]);
            a2[j] += bf2f(v2[j]); a3[j] += bf2f(v3[j]);
        }
    }
    for (; k < hi; ++k) {
        u16x4 v = Y[(size_t)srcs[k] * 128 + c];
#pragma unroll
        for (int j = 0; j < 4; ++j) a0[j] += bf2f(v[j]);
    }
    f32x4 acc = (a0 + a1) + (a2 + a3);
    u16x4 o;
#pragma unroll
    for (int j = 0; j < 4; ++j) o[j] = f2bf(acc[j]);
    T[(size_t)i * 128 + c] = o;
}

// column sum/sumsq over bf16 [M][512] -> ss[0..511], ss[512..1023]
__global__ void bn_stats_bf16(const u16x4* __restrict__ X, int M, float* __restrict__ ss) {
    int c = threadIdx.x;                                // 128 threads x 4 cols
    int rows = M / gridDim.x;
    int r0 = blockIdx.x * rows;
    f32x4 s = {}, q = {};
    for (int r = 0; r < rows; ++r) {
        u16x4 v = X[(size_t)(r0 + r) * 128 + c];
        f32x4 f;
#pragma unroll
        for (int j = 0; j < 4; ++j) f[j] = bf2f(v[j]);
        s += f; q += f * f;
    }
#pragma unroll
    for (int j = 0; j < 4; ++j) {
        atomicAdd(&ss[c * 4 + j], s[j]);
        atomicAdd(&ss[512 + c * 4 + j], q[j]);
    }
}

// bn finalize+apply+ReLU, bf16 in -> bf16 out (strided, optional scale)
__global__ void bn_apply(const u16x4* __restrict__ X, int M, const float* __restrict__ ss,
                         const float* __restrict__ g, const float* __restrict__ b,
                         unsigned short* __restrict__ out, int ostride, int ooff,
                         const float* __restrict__ scale) {
    int c = threadIdx.x;                                // 128 threads x 4 cols
    float inv = 1.0f / (float)M;
    float al[4], be[4];
#pragma unroll
    for (int i = 0; i < 4; ++i) {
        float mean = ss[c * 4 + i] * inv;
        float var  = ss[512 + c * 4 + i] * inv - mean * mean;
        al[i] = g[c * 4 + i] * rsqrtf(var + 1e-5f);
        be[i] = b[c * 4 + i] - mean * al[i];
    }
    float sc = scale ? *scale : 1.0f;
    int rows = M / gridDim.x;
    int r0 = blockIdx.x * rows;
    for (int r = 0; r < rows; ++r) {
        u16x4 v = X[(size_t)(r0 + r) * 128 + c];
        u16x4 h;
#pragma unroll
        for (int i = 0; i < 4; ++i)
            h[i] = f2bf(fmaxf(al[i] * bf2f(v[i]) + be[i], 0.f) * sc);
        *reinterpret_cast<u16x4*>(out + (size_t)(r0 + r) * ostride + ooff + c * 4) = h;
    }
}

// contiguous f32 -> bf16 convert
__global__ void cvt_bf16(const f32x4* __restrict__ X, u16x4* __restrict__ out, int n4) {
    for (int i = blockIdx.x * blockDim.x + threadIdx.x; i < n4; i += gridDim.x * blockDim.x) {
        f32x4 v = X[i];
        u16x4 h;
#pragma unroll
        for (int j = 0; j < 4; ++j) h[j] = f2bf(v[j]);
        out[i] = h;
    }
}

// ---------------------------------------------------------------------------
// motif transpose: S f32 [4096][8192] -> D bf16 [8192][4096], 64x64 tiles
// ---------------------------------------------------------------------------
__global__ __launch_bounds__(256) void motif_transpose(const float* __restrict__ S,
                                                       unsigned short* __restrict__ D) {
    __shared__ unsigned short tile[64][66];
    int m0 = blockIdx.x * 64;
    int k0 = blockIdx.y * 64;
    int t = threadIdx.x;
    int r = t >> 4, cq = t & 15;
#pragma unroll
    for (int p = 0; p < 4; ++p) {
        int row = r + p * 16;
        f32x4 v = *reinterpret_cast<const f32x4*>(S + (size_t)(k0 + row) * 8192 + m0 + cq * 4);
        u16x4 h;
#pragma unroll
        for (int j = 0; j < 4; ++j) h[j] = f2bf(v[j]);
        *reinterpret_cast<u16x4*>(&tile[row][cq * 4]) = h;
    }
    __syncthreads();
#pragma unroll
    for (int p = 0; p < 4; ++p) {
        int col = r + p * 16;
        u16x4 h;
#pragma unroll
        for (int i = 0; i < 4; ++i) h[i] = tile[cq * 4 + i][col];
        *reinterpret_cast<u16x4*>(D + (size_t)(m0 + col) * 4096 + k0 + cq * 4) = h;
    }
}

// ---------------------------------------------------------------------------
// small transposes (weights), batched
// ---------------------------------------------------------------------------
__global__ void transpose_cvt_b(const float* __restrict__ S, unsigned short* __restrict__ D,
                                int rows, int cols, size_t sstride, size_t dstride) {
    S += blockIdx.z * sstride; D += blockIdx.z * dstride;
    __shared__ unsigned short tile[32][33];
    int x0 = blockIdx.x * 32, y0 = blockIdx.y * 32;
    for (int j = threadIdx.y; j < 32; j += blockDim.y)
        tile[j][threadIdx.x] = f2bf(S[(size_t)(y0 + j) * cols + x0 + threadIdx.x]);
    __syncthreads();
    for (int j = threadIdx.y; j < 32; j += blockDim.y)
        D[(size_t)(x0 + j) * rows + y0 + threadIdx.x] = tile[threadIdx.x][j];
}

// 11 square 512x512 weights in one launch
__global__ void transpose_cvt11(const float* __restrict__ A, unsigned short* __restrict__ Ad,
                                const float* __restrict__ B, unsigned short* __restrict__ Bd,
                                const float* __restrict__ Cs, unsigned short* __restrict__ Cd) {
    int z = blockIdx.z;
    const float* S; unsigned short* D;
    if (z < 4)      { S = A  + (size_t)z * 262144;       D = Ad + (size_t)z * 262144; }
    else if (z < 7) { S = B  + (size_t)(z - 4) * 262144; D = Bd + (size_t)(z - 4) * 262144; }
    else            { S = Cs + (size_t)(z - 7) * 262144; D = Cd + (size_t)(z - 7) * 262144; }
    __shared__ unsigned short tile[32][33];
    int x0 = blockIdx.x * 32, y0 = blockIdx.y * 32;
    for (int j = threadIdx.y; j < 32; j += blockDim.y)
        tile[j][threadIdx.x] = f2bf(S[(size_t)(y0 + j) * 512 + x0 + threadIdx.x]);
    __syncthreads();
    for (int j = threadIdx.y; j < 32; j += blockDim.y)
        D[(size_t)(x0 + j) * 512 + y0 + threadIdx.x] = tile[threadIdx.x][j];
}

__global__ void transpose_bf16(const unsigned short* __restrict__ S, unsigned short* __restrict__ D,
                               int rows, int cols) {
    __shared__ unsigned short tile[32][33];
    int x0 = blockIdx.x * 32, y0 = blockIdx.y * 32;
    for (int j = threadIdx.y; j < 32; j += blockDim.y)
        tile[j][threadIdx.x] = S[(size_t)(y0 + j) * cols + x0 + threadIdx.x];
    __syncthreads();
    for (int j = threadIdx.y; j < 32; j += blockDim.y)
        D[(size_t)(x0 + j) * rows + y0 + threadIdx.x] = tile[threadIdx.x][j];
}

// ---------------------------------------------------------------------------
// graph pooling (sorted graph_ids); row-chunked, atomic accumulate into P
// ---------------------------------------------------------------------------
__device__ __forceinline__ int lbound(const int* __restrict__ a, int n, int v) {
    int lo = 0, hi = n;
    while (lo < hi) { int m = (lo + hi) >> 1; if (a[m] < v) lo = m + 1; else hi = m; }
    return lo;
}

// grid (64, 8), 256 threads x4 cols of 1024; P pre-zeroed
__global__ void pool_bf16_at(const u16x4* __restrict__ Hm, const int* __restrict__ gid,
                             int n, float* __restrict__ P) {
    int g = blockIdx.x;
    int lo = lbound(gid, n, g), hi = lbound(gid, n, g + 1);
    int cnt = hi - lo;
    int per = (cnt + 7) >> 3;
    int s = lo + blockIdx.y * per;
    int e = min(s + per, hi);
    if (s >= e) return;
    int c = threadIdx.x;
    f32x4 acc = {};
    for (int i = s; i < e; ++i) {
        u16x4 v = Hm[(size_t)i * 256 + c];
#pragma unroll
        for (int j = 0; j < 4; ++j) acc[j] += bf2f(v[j]);
    }
#pragma unroll
    for (int j = 0; j < 4; ++j)
        atomicAdd(&P[(size_t)g * 1024 + c * 4 + j], acc[j]);
}

// grid (64, 4), 32 threads x4 cols of 128; P pre-zeroed (f32 input, x1 pooling)
__global__ void pool_f32_at(const float* __restrict__ Hm, const int* __restrict__ gid,
                            int n, float* __restrict__ P) {
    int g = blockIdx.x;
    int lo = lbound(gid, n, g), hi = lbound(gid, n, g + 1);
    int cnt = hi - lo;
    int per = (cnt + 3) >> 2;
    int s = lo + blockIdx.y * per;
    int e = min(s + per, hi);
    if (s >= e) return;
    int c = threadIdx.x;
    f32x4 acc = {};
    for (int i = s; i < e; ++i)
        acc += *reinterpret_cast<const f32x4*>(Hm + (size_t)i * 128 + c * 4);
#pragma unroll
    for (int j = 0; j < 4; ++j)
        atomicAdd(&P[(size_t)g * 128 + c * 4 + j], acc[j]);
}

__global__ void softmax2(const float* __restrict__ atts, float* __restrict__ a) {
    if (threadIdx.x == 0) {
        float m = fmaxf(atts[0], atts[1]);
        float e0 = expf(atts[0] - m), e1 = expf(atts[1] - m);
        float inv = 1.0f / (e0 + e1);
        a[0] = e0 * inv; a[1] = e1 * inv;
    }
}

// score[g,o] = P0[g]@W0 + b0 + sum_l PL[l][g]@W[l] + b[l]
__global__ __launch_bounds__(256) void score_kernel(
    const float* __restrict__ P0, const float* __restrict__ PL,
    const float* __restrict__ W0, const float* __restrict__ b0,
    const float* __restrict__ W, const float* __restrict__ bb,
    float* __restrict__ out)
{
    int g = blockIdx.x;
    int t = threadIdx.x;
    float part[10];
#pragma unroll
    for (int o = 0; o < 10; ++o) part[o] = 0.f;
    if (t < 128) {
        float p = P0[g * 128 + t];
#pragma unroll
        for (int o = 0; o < 10; ++o) part[o] += p * W0[t * 10 + o];
    }
    for (int l = 0; l < 4; ++l) {
        const float* p = PL + (size_t)l * 65536 + (size_t)g * 1024;
        const float* w = W + (size_t)l * 10240;
        for (int k = t; k < 1024; k += 256) {
            float pv = p[k];
#pragma unroll
            for (int o = 0; o < 10; ++o) part[o] += pv * w[k * 10 + o];
        }
    }
    __shared__ float red[4][10];
#pragma unroll
    for (int o = 0; o < 10; ++o) {
        float v = part[o];
        for (int off = 32; off; off >>= 1) v += __shfl_down(v, off, 64);
        if ((t & 63) == 0) red[t >> 6][o] = v;
    }
    __syncthreads();
    if (t < 10) {
        float s = b0[t] + red[0][t] + red[1][t] + red[2][t] + red[3][t];
#pragma unroll
        for (int l = 0; l < 4; ++l) s += bb[l * 10 + t];
        out[g * 10 + t] = s;
    }
}

// ---------------------------------------------------------------------------
// host orchestration
// ---------------------------------------------------------------------------
static void launch_gemm(const unsigned short* A, const unsigned short* Bt,
                        int M, int N, int K, unsigned short* Cb,
                        int ostride, int ooff, const float* scalep, float* statp,
                        hipStream_t s) {
    if (M % 128 == 0 && M >= 8192)
        gemm_bf16<128><<<dim3(M / 128, N / 128), 256, 0, s>>>(A, Bt, M, N, K, Cb, ostride, ooff, scalep, statp, nullptr);
    else
        gemm_bf16<64><<<dim3(M / 64, N / 128), 256, 0, s>>>(A, Bt, M, N, K, Cb, ostride, ooff, scalep, statp, nullptr);
}

extern "C" void kernel_launch(void* const* d_in, const int* in_sizes, int n_in,
                              void* d_out, int out_size, void* d_ws, size_t ws_size,
                              hipStream_t stream) {
    const float* x1    = (const float*)d_in[0];
    const float* x2    = (const float*)d_in[1];
    const float* motif = (const float*)d_in[2];
    const int*   edge1 = (const int*)d_in[3];
    const int*   edge2 = (const int*)d_in[4];
    const int*   gid   = (const int*)d_in[5];
    const float* epsv  = (const float*)d_in[6];
    const float* atts  = (const float*)d_in[7];
    const float* m1W10 = (const float*)d_in[8];
    const float* m1W1r = (const float*)d_in[9];
    const float* m1bng = (const float*)d_in[11];
    const float* m1bnb = (const float*)d_in[12];
    const float* m1W2  = (const float*)d_in[13];
    const float* bn1g  = (const float*)d_in[15];
    const float* bn1b  = (const float*)d_in[16];
    const float* m2W10 = (const float*)d_in[17];
    const float* m2W1r = (const float*)d_in[18];
    const float* m2bng = (const float*)d_in[20];
    const float* m2bnb = (const float*)d_in[21];
    const float* m2W2  = (const float*)d_in[22];
    const float* bn2g  = (const float*)d_in[24];
    const float* bn2b  = (const float*)d_in[25];
    const float* pW0   = (const float*)d_in[26];
    const float* pb0   = (const float*)d_in[27];
    const float* pW    = (const float*)d_in[28];
    const float* pb    = (const float*)d_in[29];
    float* out = (float*)d_out;

    constexpr int N1 = 8192, N2 = 4096, E1 = 262144, E2 = 65536;

    char* base = (char*)d_ws;
    size_t off = 0;
    auto alloc = [&](size_t bytes) -> void* {
        void* p = base + off;
        off = (off + bytes + 255) & ~(size_t)255;
        return p;
    };

    // bf16 buffers
    unsigned short* motifT  = (unsigned short*)alloc((size_t)8192 * 4096 * 2);
    unsigned short* w1t1_0  = (unsigned short*)alloc((size_t)512 * 128 * 2);
    unsigned short* w1t1_r  = (unsigned short*)alloc((size_t)3 * 512 * 1024 * 2);
    unsigned short* w2t1    = (unsigned short*)alloc((size_t)4 * 512 * 512 * 2);
    unsigned short* w1t2_0  = (unsigned short*)alloc((size_t)512 * 64 * 2);
    unsigned short* w1t2_r  = (unsigned short*)alloc((size_t)3 * 512 * 512 * 2);
    unsigned short* w2t2    = (unsigned short*)alloc((size_t)4 * 512 * 512 * 2);
    unsigned short* x1b     = (unsigned short*)alloc((size_t)N1 * 128 * 2);
    unsigned short* x2b     = (unsigned short*)alloc((size_t)N2 * 64 * 2);
    unsigned short* H1b     = (unsigned short*)alloc((size_t)N1 * 1024 * 2);
    unsigned short* H2b     = (unsigned short*)alloc((size_t)N2 * 512 * 2);
    unsigned short* H2t     = (unsigned short*)alloc((size_t)512 * 4096 * 2);
    unsigned short* U1b     = (unsigned short*)alloc((size_t)N1 * 512 * 2);
    unsigned short* U2b     = (unsigned short*)alloc((size_t)N2 * 512 * 2);
    unsigned short* Y1b     = (unsigned short*)alloc((size_t)N1 * 512 * 2);
    unsigned short* T1b     = (unsigned short*)alloc((size_t)N1 * 512 * 2);
    unsigned short* Y2b     = (unsigned short*)alloc((size_t)N2 * 512 * 2);
    unsigned short* T2b     = (unsigned short*)alloc((size_t)N2 * 512 * 2);
    // memset-together region: cnt1 | cnt2 | ss | PL | P0 (all 256-aligned sizes)
    int*   cnt1 = (int*)alloc((size_t)N1 * 4);
    int*   cnt2 = (int*)alloc((size_t)N2 * 4);
    float* ss   = (float*)alloc((size_t)16 * 1024 * 4);
    float* PL   = (float*)alloc((size_t)4 * 64 * 1024 * 4);
    float* P0   = (float*)alloc((size_t)64 * 128 * 4);
    const size_t zero_bytes = (size_t)N1 * 4 + N2 * 4 + 16 * 1024 * 4 + 4 * 64 * 1024 * 4 + 64 * 128 * 4;
    int*   offs1 = (int*)alloc((size_t)(N1 + 1) * 4);
    int*   offs2 = (int*)alloc((size_t)(N2 + 1) * 4);
    int*   cur1  = (int*)alloc((size_t)N1 * 4);
    int*   cur2  = (int*)alloc((size_t)N2 * 4);
    int*   srcs1 = (int*)alloc((size_t)E1 * 4);
    int*   srcs2 = (int*)alloc((size_t)E2 * 4);
    float* aDev  = (float*)alloc(256);

    if (off > ws_size) return;

    // split-K partials for the fusion GEMM: take as many of 4 splits as fit
    const size_t part_elems = (size_t)N1 * 512;
    size_t rem = ws_size - off;
    int KS = (rem >= 4 * part_elems * 4) ? 4 : (rem >= 2 * part_elems * 4) ? 2 : 1;
    float* Cpart = (float*)(base + off);

    // ---- setup ----
    hipMemsetAsync(cnt1, 0, zero_bytes, stream);
    softmax2<<<1, 64, 0, stream>>>(atts, aDev);
    cvt_bf16<<<512, 256, 0, stream>>>((const f32x4*)x1, (u16x4*)x1b, N1 * 128 / 4);
    cvt_bf16<<<256, 256, 0, stream>>>((const f32x4*)x2, (u16x4*)x2b, N2 * 64 / 4);
    motif_transpose<<<dim3(128, 64), 256, 0, stream>>>(motif, motifT);
    transpose_cvt_b<<<dim3(16, 4, 1), dim3(32, 8), 0, stream>>>(m1W10, w1t1_0, 128, 512, 0, 0);
    transpose_cvt_b<<<dim3(16, 32, 3), dim3(32, 8), 0, stream>>>(m1W1r, w1t1_r, 1024, 512,
                                                                 (size_t)1024 * 512, (size_t)512 * 1024);
    transpose_cvt_b<<<dim3(16, 2, 1), dim3(32, 8), 0, stream>>>(m2W10, w1t2_0, 64, 512, 0, 0);
    transpose_cvt11<<<dim3(16, 16, 11), dim3(32, 8), 0, stream>>>(m1W2, w2t1, m2W1r, w1t2_r, m2W2, w2t2);
    csr_count2<<<(E1 + E2) / 256, 256, 0, stream>>>(edge1, E1, cnt1, edge2, E2, cnt2);
    csr_scan2<<<2, 1024, 0, stream>>>(cnt1, N1, offs1, cur1, cnt2, N2, offs2, cur2);
    csr_fill2<<<(E1 + E2) / 256, 256, 0, stream>>>(edge1, E1, cur1, srcs1, edge2, E2, cur2, srcs2);
    pool_f32_at<<<dim3(64, 4), 32, 0, stream>>>(x1, gid, N1, P0);

    // ---- layers ----
    for (int l = 0; l < 4; ++l) {
        float* ssl = ss + (size_t)l * 4096;   // 4 slots of 1024 per layer
        // branch 1 (base graph, M = 8192): X @ W1
        launch_gemm(l ? H1b : x1b,
                    l ? w1t1_r + (size_t)(l - 1) * 512 * 1024 : w1t1_0,
                    N1, 512, l ? 1024 : 128, Y1b, 512, 0, nullptr, nullptr, stream);
        // branch 2 (hyper graph, M = 4096): X @ W1
        launch_gemm(l ? H2b : x2b,
                    l ? w1t2_r + (size_t)(l - 1) * 512 * 512 : w1t2_0,
                    N2, 512, l ? 512 : 64, Y2b, 512, 0, nullptr, nullptr, stream);
        // both gathers in one dispatch
        gather2_bf16<<<N1 + N2, 128, 0, stream>>>(
            (const u16x4*)Y1b, offs1, srcs1, (u16x4*)T1b, N1,
            (const u16x4*)Y2b, offs2, srcs2, (u16x4*)T2b, epsv, l);
        bn_stats_bf16<<<512, 128, 0, stream>>>((const u16x4*)T1b, N1, ssl + 0 * 1024);
        bn_stats_bf16<<<512, 128, 0, stream>>>((const u16x4*)T2b, N2, ssl + 2 * 1024);
        bn_apply<<<1024, 128, 0, stream>>>((const u16x4*)T1b, N1, ssl + 0 * 1024,
                                           m1bng + l * 512, m1bnb + l * 512, U1b, 512, 0, nullptr);
        bn_apply<<<512, 128, 0, stream>>>((const u16x4*)T2b, N2, ssl + 2 * 1024,
                                          m2bng + l * 512, m2bnb + l * 512, U2b, 512, 0, nullptr);
        // W2 GEMMs with fused column stats
        launch_gemm(U1b, w2t1 + (size_t)l * 512 * 512, N1, 512, 512,
                    Y1b, 512, 0, nullptr, ssl + 1 * 1024, stream);
        launch_gemm(U2b, w2t2 + (size_t)l * 512 * 512, N2, 512, 512,
                    Y2b, 512, 0, nullptr, ssl + 3 * 1024, stream);
        bn_apply<<<1024, 128, 0, stream>>>((const u16x4*)Y1b, N1, ssl + 1 * 1024,
                                           bn1g + l * 512, bn1b + l * 512, H1b, 1024, 0, aDev + 0);
        bn_apply<<<512, 128, 0, stream>>>((const u16x4*)Y2b, N2, ssl + 3 * 1024,
                                          bn2g + l * 512, bn2b + l * 512, H2b, 512, 0, nullptr);
        // fusion: h2A = motif2A^T @ h2 with split-K, finalize applies a1 scale
        transpose_bf16<<<dim3(16, 128), dim3(32, 8), 0, stream>>>(H2b, H2t, N2, 512);
        if (KS > 1) {
            gemm_bf16<128><<<dim3(64, 4, KS), 256, 0, stream>>>(
                motifT, H2t, N1, 512, 4096, nullptr, 0, 0, nullptr, nullptr, Cpart);
            sumk_cvt<<<2048, 256, 0, stream>>>((const f32x4*)Cpart, KS, aDev + 1, H1b, 1024, 512);
        } else {
            launch_gemm(motifT, H2t, N1, 512, 4096, H1b, 1024, 512, aDev + 1, nullptr, stream);
        }
        // jumping-knowledge pooling of hidden[l+1]
        pool_bf16_at<<<dim3(64, 8), 256, 0, stream>>>((const u16x4*)H1b, gid, N1,
                                                      PL + (size_t)l * 64 * 1024);
    }

    score_kernel<<<64, 256, 0, stream>>>(P0, PL, pW0, pb0, pW, pb, out);
}

// Round 6
// 1028.499 us; speedup vs baseline: 2.8459x; 1.2999x over previous
//
#include <hip/hip_runtime.h>

// ---------------------------------------------------------------------------
// types & helpers
// ---------------------------------------------------------------------------
using bf16x8 = __attribute__((ext_vector_type(8))) short;
using f32x4  = __attribute__((ext_vector_type(4))) float;
using u16x4  = __attribute__((ext_vector_type(4))) unsigned short;
using as3_void  = __attribute__((address_space(3))) void;
using as1_cvoid = const __attribute__((address_space(1))) void;

__device__ __forceinline__ unsigned short f2bf(float x) {
    union { float f; unsigned u; } v; v.f = x;
    unsigned r = v.u + 0x7FFFu + ((v.u >> 16) & 1u);   // RNE
    return (unsigned short)(r >> 16);
}
__device__ __forceinline__ float bf2f(unsigned short h) {
    union { unsigned u; float f; } v; v.u = ((unsigned)h) << 16;
    return v.f;
}

// ---------------------------------------------------------------------------
// GEMM tile body shared by both kernels: BM x 128, BK=64, 4 waves (2x2),
// LDS XOR-swizzle on the GLOBAL source; ds_read applies the same swizzle.
// ---------------------------------------------------------------------------
#define GEMM_BODY(BM, A, Bt, K, KBEG, KEND)                                          \
    constexpr int WROWS = (BM) / 2;                                                  \
    constexpr int MI = WROWS / 16;                                                   \
    __shared__ __align__(16) unsigned short As[(BM) * 64];                           \
    __shared__ __align__(16) unsigned short Bs[128 * 64];                            \
    const int tid  = threadIdx.x;                                                    \
    const int lane = tid & 63, wave = tid >> 6;                                      \
    const int wr = wave >> 1, wc = wave & 1;                                         \
    const int rl = lane & 15, kg = lane >> 4;                                        \
    f32x4 acc[MI][4] = {};                                                           \
    for (int kt = (KBEG); kt < (KEND); kt += 64) {                                   \
        _Pragma("unroll")                                                            \
        for (int it = 0; it < (BM) / 32; ++it) {                                     \
            int slot = it * 256 + tid;                                               \
            int r = slot >> 3, c = slot & 7;                                         \
            int cg = c ^ (r & 7);                                                    \
            const unsigned short* ga = (A) + (size_t)(m0 + r) * (K) + (kt + cg * 8); \
            __builtin_amdgcn_global_load_lds((as1_cvoid*)ga, (as3_void*)(As + slot * 8), 16, 0, 0); \
        }                                                                            \
        _Pragma("unroll")                                                            \
        for (int it = 0; it < 4; ++it) {                                             \
            int slot = it * 256 + tid;                                               \
            int r = slot >> 3, c = slot & 7;                                         \
            int cg = c ^ (r & 7);                                                    \
            const unsigned short* gb = (Bt) + (size_t)(n0 + r) * (K) + (kt + cg * 8);\
            __builtin_amdgcn_global_load_lds((as1_cvoid*)gb, (as3_void*)(Bs + slot * 8), 16, 0, 0); \
        }                                                                            \
        __syncthreads();                                                             \
        _Pragma("unroll")                                                            \
        for (int kh = 0; kh < 2; ++kh) {                                             \
            bf16x8 a_[MI], b_[4];                                                    \
            _Pragma("unroll")                                                        \
            for (int i = 0; i < MI; ++i) {                                           \
                int ra = wr * WROWS + i * 16 + rl;                                   \
                int ca = (kh * 4 + kg) ^ (ra & 7);                                   \
                a_[i] = *reinterpret_cast<const bf16x8*>(&As[ra * 64 + ca * 8]);     \
            }                                                                        \
            _Pragma("unroll")                                                        \
            for (int j = 0; j < 4; ++j) {                                            \
                int rb = wc * 64 + j * 16 + rl;                                      \
                int cb = (kh * 4 + kg) ^ (rb & 7);                                   \
                b_[j] = *reinterpret_cast<const bf16x8*>(&Bs[rb * 64 + cb * 8]);     \
            }                                                                        \
            _Pragma("unroll")                                                        \
            for (int i = 0; i < MI; ++i)                                             \
                _Pragma("unroll")                                                    \
                for (int j = 0; j < 4; ++j)                                          \
                    acc[i][j] = __builtin_amdgcn_mfma_f32_16x16x32_bf16(a_[i], b_[j], acc[i][j], 0, 0, 0); \
        }                                                                            \
        __syncthreads();                                                             \
    }

// ---------------------------------------------------------------------------
// dual-job GEMM (BM=64): blockIdx.x < nb0 -> job0, else job1. bf16 out,
// optional fused BN column stats (sum/sumsq atomicAdd into statp[1024]).
// ---------------------------------------------------------------------------
__global__ __launch_bounds__(256) void gemm_dual(
    int nb0,
    const unsigned short* __restrict__ A0, const unsigned short* __restrict__ B0,
    int K0, unsigned short* __restrict__ C0, int os0, int oo0, float* __restrict__ st0,
    const unsigned short* __restrict__ A1, const unsigned short* __restrict__ B1,
    int K1, unsigned short* __restrict__ C1, int os1, int oo1, float* __restrict__ st1)
{
    int bx = blockIdx.x;
    const unsigned short *A, *Bt; unsigned short* Cb; float* statp;
    int K, ostride, ooff;
    if (bx < nb0) { A = A0; Bt = B0; K = K0; Cb = C0; ostride = os0; ooff = oo0; statp = st0; }
    else { bx -= nb0; A = A1; Bt = B1; K = K1; Cb = C1; ostride = os1; ooff = oo1; statp = st1; }
    const int m0 = bx * 64, n0 = blockIdx.y * 128;

    GEMM_BODY(64, A, Bt, K, 0, K)

#pragma unroll
    for (int i = 0; i < MI; ++i)
#pragma unroll
        for (int j = 0; j < 4; ++j)
#pragma unroll
            for (int e = 0; e < 4; ++e) {
                int rr = m0 + wr * WROWS + i * 16 + kg * 4 + e;
                int cc = n0 + wc * 64 + j * 16 + rl;
                Cb[(size_t)rr * ostride + ooff + cc] = f2bf(acc[i][j][e]);
            }
    if (statp) {
#pragma unroll
        for (int j = 0; j < 4; ++j) {
            float s = 0.f, q = 0.f;
#pragma unroll
            for (int i = 0; i < MI; ++i)
#pragma unroll
                for (int e = 0; e < 4; ++e) {
                    float x = acc[i][j][e];
                    s += x; q += x * x;
                }
            s += __shfl_xor(s, 16); s += __shfl_xor(s, 32);
            q += __shfl_xor(q, 16); q += __shfl_xor(q, 32);
            if (kg == 0) {
                int cc = n0 + wc * 64 + j * 16 + rl;
                atomicAdd(&statp[cc], s);
                atomicAdd(&statp[512 + cc], q);
            }
        }
    }
}

// ---------------------------------------------------------------------------
// fusion GEMM (BM=128), split-K over grid.z: f32 partials
// ---------------------------------------------------------------------------
__global__ __launch_bounds__(256) void gemm_splitk(
    const unsigned short* __restrict__ A, const unsigned short* __restrict__ Bt,
    int M, int N, int K, float* __restrict__ Cp)
{
    const int m0 = blockIdx.x * 128, n0 = blockIdx.y * 128;
    const int kn = K / gridDim.z, kbeg = blockIdx.z * kn;

    GEMM_BODY(128, A, Bt, K, kbeg, kbeg + kn)

    float* dst = Cp + (size_t)blockIdx.z * M * N;
#pragma unroll
    for (int i = 0; i < MI; ++i)
#pragma unroll
        for (int j = 0; j < 4; ++j)
#pragma unroll
            for (int e = 0; e < 4; ++e) {
                int rr = m0 + wr * WROWS + i * 16 + kg * 4 + e;
                int cc = n0 + wc * 64 + j * 16 + rl;
                dst[(size_t)rr * N + cc] = acc[i][j][e];
            }
}

// sum KS partials (8192x512), scale, cvt bf16, strided store into H1b[:,512:],
// plus fused JK pooling into pool[g*1024 + 512 + col] (gid sorted).
__global__ __launch_bounds__(128) void sumk_cvt_pool(
    const f32x4* __restrict__ P, int ks, const float* __restrict__ scalep,
    unsigned short* __restrict__ out, const int* __restrict__ gid,
    float* __restrict__ pool)
{
    const int total4 = 8192 * 128;
    float sc = *scalep;
    int c = threadIdx.x;
    int r0 = blockIdx.x * 8;
    int curg = gid[r0];
    f32x4 pacc = {};
    for (int r = 0; r < 8; ++r) {
        int row = r0 + r;
        f32x4 s = P[(size_t)row * 128 + c];
        for (int z = 1; z < ks; ++z) s += P[(size_t)z * total4 + (size_t)row * 128 + c];
        u16x4 h;
        f32x4 f;
#pragma unroll
        for (int j = 0; j < 4; ++j) { h[j] = f2bf(s[j] * sc); f[j] = bf2f(h[j]); }
        *reinterpret_cast<u16x4*>(out + (size_t)row * 1024 + 512 + c * 4) = h;
        int g = gid[row];
        if (g != curg) {
#pragma unroll
            for (int j = 0; j < 4; ++j) atomicAdd(&pool[(size_t)curg * 1024 + 512 + c * 4 + j], pacc[j]);
            pacc = {}; curg = g;
        }
        pacc += f;
    }
#pragma unroll
    for (int j = 0; j < 4; ++j) atomicAdd(&pool[(size_t)curg * 1024 + 512 + c * 4 + j], pacc[j]);
}

// ---------------------------------------------------------------------------
// CSR build
// ---------------------------------------------------------------------------
__global__ void csr_count2(const int* __restrict__ e1, int E1, int* __restrict__ c1,
                           const int* __restrict__ e2, int E2, int* __restrict__ c2) {
    int i = blockIdx.x * 256 + threadIdx.x;
    if (i < E1) atomicAdd(&c1[e1[i]], 1);
    else if (i < E1 + E2) atomicAdd(&c2[e2[i - E1]], 1);
}

__global__ void csr_scan2(const int* __restrict__ cnt1, int n1, int* __restrict__ offs1, int* __restrict__ cur1,
                          const int* __restrict__ cnt2, int n2, int* __restrict__ offs2, int* __restrict__ cur2) {
    const int* cnt = blockIdx.x ? cnt2 : cnt1;
    int n           = blockIdx.x ? n2 : n1;
    int* offs       = blockIdx.x ? offs2 : offs1;
    int* cursor     = blockIdx.x ? cur2 : cur1;
    __shared__ int part[1024];
    int t = threadIdx.x;
    int per = n >> 10;
    int base = t * per;
    int loc[8];
    int s = 0;
    for (int j = 0; j < per; ++j) { loc[j] = s; s += cnt[base + j]; }
    part[t] = s;
    __syncthreads();
    for (int o = 1; o < 1024; o <<= 1) {
        int v = (t >= o) ? part[t - o] : 0;
        __syncthreads();
        part[t] += v;
        __syncthreads();
    }
    int excl = (t == 0) ? 0 : part[t - 1];
    for (int j = 0; j < per; ++j) {
        int v = excl + loc[j];
        offs[base + j] = v;
        cursor[base + j] = v;
    }
    if (t == 1023) offs[n] = part[1023];
}

__global__ void csr_fill2(const int* __restrict__ e1, int E1, int* __restrict__ cur1, int* __restrict__ s1,
                          const int* __restrict__ e2, int E2, int* __restrict__ cur2, int* __restrict__ s2) {
    int i = blockIdx.x * 256 + threadIdx.x;
    if (i < E1) {
        int d = e1[i], s = e1[E1 + i];
        s1[atomicAdd(&cur1[d], 1)] = s;
    } else if (i < E1 + E2) {
        int e = i - E1;
        int d = e2[e], s = e2[E2 + e];
        s2[atomicAdd(&cur2[d], 1)] = s;
    }
}

// ---------------------------------------------------------------------------
// gather for BOTH branches in one dispatch (512 cols, one block per row)
// ---------------------------------------------------------------------------
__global__ __launch_bounds__(128) void gather2_bf16(
    const u16x4* __restrict__ Y1, const int* __restrict__ offs1, const int* __restrict__ srcs1,
    u16x4* __restrict__ T1, int n1,
    const u16x4* __restrict__ Y2, const int* __restrict__ offs2, const int* __restrict__ srcs2,
    u16x4* __restrict__ T2,
    const float* __restrict__ epsv, int l)
{
    int i = blockIdx.x;
    const u16x4* Y; u16x4* T; const int *offs, *srcs;
    if (i < n1) { Y = Y1; T = T1; offs = offs1; srcs = srcs1; }
    else        { i -= n1; Y = Y2; T = T2; offs = offs2; srcs = srcs2; }
    int c = threadIdx.x;
    float e = 1.0f + epsv[l];
    int lo = offs[i], hi = offs[i + 1];
    u16x4 hv = Y[(size_t)i * 128 + c];
    f32x4 a0, a1 = {}, a2 = {}, a3 = {};
#pragma unroll
    for (int j = 0; j < 4; ++j) a0[j] = e * bf2f(hv[j]);
    int k = lo;
    for (; k + 4 <= hi; k += 4) {
        int s0 = srcs[k], s1 = srcs[k + 1], s2 = srcs[k + 2], s3 = srcs[k + 3];
        u16x4 v0 = Y[(size_t)s0 * 128 + c];
        u16x4 v1 = Y[(size_t)s1 * 128 + c];
        u16x4 v2 = Y[(size_t)s2 * 128 + c];
        u16x4 v3 = Y[(size_t)s3 * 128 + c];
#pragma unroll
        for (int j = 0; j < 4; ++j) {
            a0[j] += bf2f(v0[j]); a1[j] += bf2f(v1[j]);
            a2[j] += bf2f(v2[j]); a3[j] += bf2f(v3[j]);
        }
    }
    for (; k < hi; ++k) {
        u16x4 v = Y[(size_t)srcs[k] * 128 + c];
#pragma unroll
        for (int j = 0; j < 4; ++j) a0[j] += bf2f(v[j]);
    }
    f32x4 acc = (a0 + a1) + (a2 + a3);
    u16x4 o;
#pragma unroll
    for (int j = 0; j < 4; ++j) o[j] = f2bf(acc[j]);
    T[(size_t)i * 128 + c] = o;
}

// ---------------------------------------------------------------------------
// dual column sum/sumsq over bf16 [M][512]: job0 = 512 blocks x16 rows,
// job1 = 256 blocks x16 rows
// ---------------------------------------------------------------------------
__global__ void bn_stats2(int nb0,
                          const u16x4* __restrict__ X0, float* __restrict__ ss0,
                          const u16x4* __restrict__ X1, float* __restrict__ ss1) {
    int bx = blockIdx.x;
    const u16x4* X; float* ss;
    if (bx < nb0) { X = X0; ss = ss0; }
    else { bx -= nb0; X = X1; ss = ss1; }
    int c = threadIdx.x;
    int r0 = bx * 16;
    f32x4 s = {}, q = {};
    for (int r = 0; r < 16; ++r) {
        u16x4 v = X[(size_t)(r0 + r) * 128 + c];
        f32x4 f;
#pragma unroll
        for (int j = 0; j < 4; ++j) f[j] = bf2f(v[j]);
        s += f; q += f * f;
    }
#pragma unroll
    for (int j = 0; j < 4; ++j) {
        atomicAdd(&ss[c * 4 + j], s[j]);
        atomicAdd(&ss[512 + c * 4 + j], q[j]);
    }
}

// ---------------------------------------------------------------------------
// dual bn finalize+apply+ReLU (8 rows/block), optional scale, optional fused
// JK pooling (gid sorted) into pool[g*1024 + ooff + col]
// ---------------------------------------------------------------------------
__global__ __launch_bounds__(128) void bn_apply2(
    int nb0, const int* __restrict__ gid,
    const u16x4* __restrict__ X0, int M0, const float* __restrict__ ss0,
    const float* __restrict__ g0, const float* __restrict__ b0,
    unsigned short* __restrict__ o0, int os0, int oo0,
    const float* __restrict__ sc0, float* __restrict__ pool0,
    const u16x4* __restrict__ X1, int M1, const float* __restrict__ ss1,
    const float* __restrict__ g1, const float* __restrict__ b1,
    unsigned short* __restrict__ o1, int os1, int oo1,
    const float* __restrict__ sc1, float* __restrict__ pool1)
{
    int bx = blockIdx.x;
    const u16x4* X; const float *ss, *g, *b, *scp; unsigned short* out;
    int M, ostride, ooff; float* pool;
    if (bx < nb0) { X = X0; M = M0; ss = ss0; g = g0; b = b0; out = o0; ostride = os0; ooff = oo0; scp = sc0; pool = pool0; }
    else { bx -= nb0; X = X1; M = M1; ss = ss1; g = g1; b = b1; out = o1; ostride = os1; ooff = oo1; scp = sc1; pool = pool1; }
    int c = threadIdx.x;
    float inv = 1.0f / (float)M;
    float al[4], be[4];
#pragma unroll
    for (int i = 0; i < 4; ++i) {
        float mean = ss[c * 4 + i] * inv;
        float var  = ss[512 + c * 4 + i] * inv - mean * mean;
        al[i] = g[c * 4 + i] * rsqrtf(var + 1e-5f);
        be[i] = b[c * 4 + i] - mean * al[i];
    }
    float sc = scp ? *scp : 1.0f;
    int r0 = bx * 8;
    int curg = pool ? gid[r0] : 0;
    f32x4 pacc = {};
    for (int r = 0; r < 8; ++r) {
        int row = r0 + r;
        u16x4 v = X[(size_t)row * 128 + c];
        u16x4 h;
        f32x4 f;
#pragma unroll
        for (int i = 0; i < 4; ++i) {
            h[i] = f2bf(fmaxf(al[i] * bf2f(v[i]) + be[i], 0.f) * sc);
            f[i] = bf2f(h[i]);
        }
        *reinterpret_cast<u16x4*>(out + (size_t)row * ostride + ooff + c * 4) = h;
        if (pool) {
            int gg = gid[row];
            if (gg != curg) {
#pragma unroll
                for (int j = 0; j < 4; ++j) atomicAdd(&pool[(size_t)curg * 1024 + ooff + c * 4 + j], pacc[j]);
                pacc = {}; curg = gg;
            }
            pacc += f;
        }
    }
    if (pool) {
#pragma unroll
        for (int j = 0; j < 4; ++j) atomicAdd(&pool[(size_t)curg * 1024 + ooff + c * 4 + j], pacc[j]);
    }
}

// contiguous f32 -> bf16 convert
__global__ void cvt_bf16(const f32x4* __restrict__ X, u16x4* __restrict__ out, int n4) {
    for (int i = blockIdx.x * blockDim.x + threadIdx.x; i < n4; i += gridDim.x * blockDim.x) {
        f32x4 v = X[i];
        u16x4 h;
#pragma unroll
        for (int j = 0; j < 4; ++j) h[j] = f2bf(v[j]);
        out[i] = h;
    }
}

// ---------------------------------------------------------------------------
// motif transpose: S f32 [4096][8192] -> D bf16 [8192][4096], 64x64 tiles
// ---------------------------------------------------------------------------
__global__ __launch_bounds__(256) void motif_transpose(const float* __restrict__ S,
                                                       unsigned short* __restrict__ D) {
    __shared__ unsigned short tile[64][66];
    int m0 = blockIdx.x * 64;
    int k0 = blockIdx.y * 64;
    int t = threadIdx.x;
    int r = t >> 4, cq = t & 15;
#pragma unroll
    for (int p = 0; p < 4; ++p) {
        int row = r + p * 16;
        f32x4 v = *reinterpret_cast<const f32x4*>(S + (size_t)(k0 + row) * 8192 + m0 + cq * 4);
        u16x4 h;
#pragma unroll
        for (int j = 0; j < 4; ++j) h[j] = f2bf(v[j]);
        *reinterpret_cast<u16x4*>(&tile[row][cq * 4]) = h;
    }
    __syncthreads();
#pragma unroll
    for (int p = 0; p < 4; ++p) {
        int col = r + p * 16;
        u16x4 h;
#pragma unroll
        for (int i = 0; i < 4; ++i) h[i] = tile[cq * 4 + i][col];
        *reinterpret_cast<u16x4*>(D + (size_t)(m0 + col) * 4096 + k0 + cq * 4) = h;
    }
}

// ---------------------------------------------------------------------------
// small transposes (weights), batched
// ---------------------------------------------------------------------------
__global__ void transpose_cvt_b(const float* __restrict__ S, unsigned short* __restrict__ D,
                                int rows, int cols, size_t sstride, size_t dstride) {
    S += blockIdx.z * sstride; D += blockIdx.z * dstride;
    __shared__ unsigned short tile[32][33];
    int x0 = blockIdx.x * 32, y0 = blockIdx.y * 32;
    for (int j = threadIdx.y; j < 32; j += blockDim.y)
        tile[j][threadIdx.x] = f2bf(S[(size_t)(y0 + j) * cols + x0 + threadIdx.x]);
    __syncthreads();
    for (int j = threadIdx.y; j < 32; j += blockDim.y)
        D[(size_t)(x0 + j) * rows + y0 + threadIdx.x] = tile[threadIdx.x][j];
}

// 11 square 512x512 weights in one launch
__global__ void transpose_cvt11(const float* __restrict__ A, unsigned short* __restrict__ Ad,
                                const float* __restrict__ B, unsigned short* __restrict__ Bd,
                                const float* __restrict__ Cs, unsigned short* __restrict__ Cd) {
    int z = blockIdx.z;
    const float* S; unsigned short* D;
    if (z < 4)      { S = A  + (size_t)z * 262144;       D = Ad + (size_t)z * 262144; }
    else if (z < 7) { S = B  + (size_t)(z - 4) * 262144; D = Bd + (size_t)(z - 4) * 262144; }
    else            { S = Cs + (size_t)(z - 7) * 262144; D = Cd + (size_t)(z - 7) * 262144; }
    __shared__ unsigned short tile[32][33];
    int x0 = blockIdx.x * 32, y0 = blockIdx.y * 32;
    for (int j = threadIdx.y; j < 32; j += blockDim.y)
        tile[j][threadIdx.x] = f2bf(S[(size_t)(y0 + j) * 512 + x0 + threadIdx.x]);
    __syncthreads();
    for (int j = threadIdx.y; j < 32; j += blockDim.y)
        D[(size_t)(x0 + j) * 512 + y0 + threadIdx.x] = tile[threadIdx.x][j];
}

__global__ void transpose_bf16(const unsigned short* __restrict__ S, unsigned short* __restrict__ D,
                               int rows, int cols) {
    __shared__ unsigned short tile[32][33];
    int x0 = blockIdx.x * 32, y0 = blockIdx.y * 32;
    for (int j = threadIdx.y; j < 32; j += blockDim.y)
        tile[j][threadIdx.x] = S[(size_t)(y0 + j) * cols + x0 + threadIdx.x];
    __syncthreads();
    for (int j = threadIdx.y; j < 32; j += blockDim.y)
        D[(size_t)(x0 + j) * rows + y0 + threadIdx.x] = tile[threadIdx.x][j];
}

// ---------------------------------------------------------------------------
// x1 graph pooling (f32, 128 cols), row-chunked, atomics into pre-zeroed P0
// ---------------------------------------------------------------------------
__device__ __forceinline__ int lbound(const int* __restrict__ a, int n, int v) {
    int lo = 0, hi = n;
    while (lo < hi) { int m = (lo + hi) >> 1; if (a[m] < v) lo = m + 1; else hi = m; }
    return lo;
}

__global__ void pool_f32_at(const float* __restrict__ Hm, const int* __restrict__ gid,
                            int n, float* __restrict__ P) {
    int g = blockIdx.x;
    int lo = lbound(gid, n, g), hi = lbound(gid, n, g + 1);
    int cnt = hi - lo;
    int per = (cnt + 3) >> 2;
    int s = lo + blockIdx.y * per;
    int e = min(s + per, hi);
    if (s >= e) return;
    int c = threadIdx.x;
    f32x4 acc = {};
    for (int i = s; i < e; ++i)
        acc += *reinterpret_cast<const f32x4*>(Hm + (size_t)i * 128 + c * 4);
#pragma unroll
    for (int j = 0; j < 4; ++j)
        atomicAdd(&P[(size_t)g * 128 + c * 4 + j], acc[j]);
}

__global__ void softmax2(const float* __restrict__ atts, float* __restrict__ a) {
    if (threadIdx.x == 0) {
        float m = fmaxf(atts[0], atts[1]);
        float e0 = expf(atts[0] - m), e1 = expf(atts[1] - m);
        float inv = 1.0f / (e0 + e1);
        a[0] = e0 * inv; a[1] = e1 * inv;
    }
}

// score[g,o] = P0[g]@W0 + b0 + sum_l PL[l][g]@W[l] + b[l]
__global__ __launch_bounds__(256) void score_kernel(
    const float* __restrict__ P0, const float* __restrict__ PL,
    const float* __restrict__ W0, const float* __restrict__ b0,
    const float* __restrict__ W, const float* __restrict__ bb,
    float* __restrict__ out)
{
    int g = blockIdx.x;
    int t = threadIdx.x;
    float part[10];
#pragma unroll
    for (int o = 0; o < 10; ++o) part[o] = 0.f;
    if (t < 128) {
        float p = P0[g * 128 + t];
#pragma unroll
        for (int o = 0; o < 10; ++o) part[o] += p * W0[t * 10 + o];
    }
    for (int l = 0; l < 4; ++l) {
        const float* p = PL + (size_t)l * 65536 + (size_t)g * 1024;
        const float* w = W + (size_t)l * 10240;
        for (int k = t; k < 1024; k += 256) {
            float pv = p[k];
#pragma unroll
            for (int o = 0; o < 10; ++o) part[o] += pv * w[k * 10 + o];
        }
    }
    __shared__ float red[4][10];
#pragma unroll
    for (int o = 0; o < 10; ++o) {
        float v = part[o];
        for (int off = 32; off; off >>= 1) v += __shfl_down(v, off, 64);
        if ((t & 63) == 0) red[t >> 6][o] = v;
    }
    __syncthreads();
    if (t < 10) {
        float s = b0[t] + red[0][t] + red[1][t] + red[2][t] + red[3][t];
#pragma unroll
        for (int l = 0; l < 4; ++l) s += bb[l * 10 + t];
        out[g * 10 + t] = s;
    }
}

// ---------------------------------------------------------------------------
// host orchestration
// ---------------------------------------------------------------------------
extern "C" void kernel_launch(void* const* d_in, const int* in_sizes, int n_in,
                              void* d_out, int out_size, void* d_ws, size_t ws_size,
                              hipStream_t stream) {
    const float* x1    = (const float*)d_in[0];
    const float* x2    = (const float*)d_in[1];
    const float* motif = (const float*)d_in[2];
    const int*   edge1 = (const int*)d_in[3];
    const int*   edge2 = (const int*)d_in[4];
    const int*   gid   = (const int*)d_in[5];
    const float* epsv  = (const float*)d_in[6];
    const float* atts  = (const float*)d_in[7];
    const float* m1W10 = (const float*)d_in[8];
    const float* m1W1r = (const float*)d_in[9];
    const float* m1bng = (const float*)d_in[11];
    const float* m1bnb = (const float*)d_in[12];
    const float* m1W2  = (const float*)d_in[13];
    const float* bn1g  = (const float*)d_in[15];
    const float* bn1b  = (const float*)d_in[16];
    const float* m2W10 = (const float*)d_in[17];
    const float* m2W1r = (const float*)d_in[18];
    const float* m2bng = (const float*)d_in[20];
    const float* m2bnb = (const float*)d_in[21];
    const float* m2W2  = (const float*)d_in[22];
    const float* bn2g  = (const float*)d_in[24];
    const float* bn2b  = (const float*)d_in[25];
    const float* pW0   = (const float*)d_in[26];
    const float* pb0   = (const float*)d_in[27];
    const float* pW    = (const float*)d_in[28];
    const float* pb    = (const float*)d_in[29];
    float* out = (float*)d_out;

    constexpr int N1 = 8192, N2 = 4096, E1 = 262144, E2 = 65536;

    char* base = (char*)d_ws;
    size_t off = 0;
    auto alloc = [&](size_t bytes) -> void* {
        void* p = base + off;
        off = (off + bytes + 255) & ~(size_t)255;
        return p;
    };

    // bf16 buffers
    unsigned short* motifT  = (unsigned short*)alloc((size_t)8192 * 4096 * 2);
    unsigned short* w1t1_0  = (unsigned short*)alloc((size_t)512 * 128 * 2);
    unsigned short* w1t1_r  = (unsigned short*)alloc((size_t)3 * 512 * 1024 * 2);
    unsigned short* w2t1    = (unsigned short*)alloc((size_t)4 * 512 * 512 * 2);
    unsigned short* w1t2_0  = (unsigned short*)alloc((size_t)512 * 64 * 2);
    unsigned short* w1t2_r  = (unsigned short*)alloc((size_t)3 * 512 * 512 * 2);
    unsigned short* w2t2    = (unsigned short*)alloc((size_t)4 * 512 * 512 * 2);
    unsigned short* x1b     = (unsigned short*)alloc((size_t)N1 * 128 * 2);
    unsigned short* x2b     = (unsigned short*)alloc((size_t)N2 * 64 * 2);
    unsigned short* H1b     = (unsigned short*)alloc((size_t)N1 * 1024 * 2);
    unsigned short* H2b     = (unsigned short*)alloc((size_t)N2 * 512 * 2);
    unsigned short* H2t     = (unsigned short*)alloc((size_t)512 * 4096 * 2);
    unsigned short* U1b     = (unsigned short*)alloc((size_t)N1 * 512 * 2);
    unsigned short* U2b     = (unsigned short*)alloc((size_t)N2 * 512 * 2);
    unsigned short* Y1b     = (unsigned short*)alloc((size_t)N1 * 512 * 2);
    unsigned short* T1b     = (unsigned short*)alloc((size_t)N1 * 512 * 2);
    unsigned short* Y2b     = (unsigned short*)alloc((size_t)N2 * 512 * 2);
    unsigned short* T2b     = (unsigned short*)alloc((size_t)N2 * 512 * 2);
    // memset-together region: cnt1 | cnt2 | ss | PL | P0 (all 256-aligned sizes)
    int*   cnt1 = (int*)alloc((size_t)N1 * 4);
    int*   cnt2 = (int*)alloc((size_t)N2 * 4);
    float* ss   = (float*)alloc((size_t)16 * 1024 * 4);
    float* PL   = (float*)alloc((size_t)4 * 64 * 1024 * 4);
    float* P0   = (float*)alloc((size_t)64 * 128 * 4);
    const size_t zero_bytes = (size_t)N1 * 4 + N2 * 4 + 16 * 1024 * 4 + 4 * 64 * 1024 * 4 + 64 * 128 * 4;
    int*   offs1 = (int*)alloc((size_t)(N1 + 1) * 4);
    int*   offs2 = (int*)alloc((size_t)(N2 + 1) * 4);
    int*   cur1  = (int*)alloc((size_t)N1 * 4);
    int*   cur2  = (int*)alloc((size_t)N2 * 4);
    int*   srcs1 = (int*)alloc((size_t)E1 * 4);
    int*   srcs2 = (int*)alloc((size_t)E2 * 4);
    float* aDev  = (float*)alloc(256);

    if (off > ws_size) return;

    // split-K partials for the fusion GEMM
    const size_t part_elems = (size_t)N1 * 512;
    size_t rem = ws_size - off;
    int KS = (rem >= 4 * part_elems * 4) ? 4 : (rem >= 2 * part_elems * 4) ? 2 : 1;
    float* Cpart = (float*)(base + off);

    // ---- setup ----
    hipMemsetAsync(cnt1, 0, zero_bytes, stream);
    softmax2<<<1, 64, 0, stream>>>(atts, aDev);
    cvt_bf16<<<512, 256, 0, stream>>>((const f32x4*)x1, (u16x4*)x1b, N1 * 128 / 4);
    cvt_bf16<<<256, 256, 0, stream>>>((const f32x4*)x2, (u16x4*)x2b, N2 * 64 / 4);
    motif_transpose<<<dim3(128, 64), 256, 0, stream>>>(motif, motifT);
    transpose_cvt_b<<<dim3(16, 4, 1), dim3(32, 8), 0, stream>>>(m1W10, w1t1_0, 128, 512, 0, 0);
    transpose_cvt_b<<<dim3(16, 32, 3), dim3(32, 8), 0, stream>>>(m1W1r, w1t1_r, 1024, 512,
                                                                 (size_t)1024 * 512, (size_t)512 * 1024);
    transpose_cvt_b<<<dim3(16, 2, 1), dim3(32, 8), 0, stream>>>(m2W10, w1t2_0, 64, 512, 0, 0);
    transpose_cvt11<<<dim3(16, 16, 11), dim3(32, 8), 0, stream>>>(m1W2, w2t1, m2W1r, w1t2_r, m2W2, w2t2);
    csr_count2<<<(E1 + E2) / 256, 256, 0, stream>>>(edge1, E1, cnt1, edge2, E2, cnt2);
    csr_scan2<<<2, 1024, 0, stream>>>(cnt1, N1, offs1, cur1, cnt2, N2, offs2, cur2);
    csr_fill2<<<(E1 + E2) / 256, 256, 0, stream>>>(edge1, E1, cur1, srcs1, edge2, E2, cur2, srcs2);
    pool_f32_at<<<dim3(64, 4), 32, 0, stream>>>(x1, gid, N1, P0);

    // ---- layers ----
    for (int l = 0; l < 4; ++l) {
        float* ssl = ss + (size_t)l * 4096;   // 4 slots of 1024 per layer
        float* PLl = PL + (size_t)l * 65536;
        // W1 GEMMs, both branches, one dispatch (128+64 row-blocks)
        gemm_dual<<<dim3(192, 4), 256, 0, stream>>>(
            128,
            l ? H1b : x1b, l ? w1t1_r + (size_t)(l - 1) * 512 * 1024 : w1t1_0,
            l ? 1024 : 128, Y1b, 512, 0, nullptr,
            l ? H2b : x2b, l ? w1t2_r + (size_t)(l - 1) * 512 * 512 : w1t2_0,
            l ? 512 : 64, Y2b, 512, 0, nullptr);
        // both gathers in one dispatch
        gather2_bf16<<<N1 + N2, 128, 0, stream>>>(
            (const u16x4*)Y1b, offs1, srcs1, (u16x4*)T1b, N1,
            (const u16x4*)Y2b, offs2, srcs2, (u16x4*)T2b, epsv, l);
        // BN stats for both gather outputs
        bn_stats2<<<768, 128, 0, stream>>>(512, (const u16x4*)T1b, ssl + 0 * 1024,
                                           (const u16x4*)T2b, ssl + 2 * 1024);
        // mid BN apply, both branches
        bn_apply2<<<1536, 128, 0, stream>>>(
            1024, gid,
            (const u16x4*)T1b, N1, ssl + 0 * 1024, m1bng + l * 512, m1bnb + l * 512,
            U1b, 512, 0, nullptr, nullptr,
            (const u16x4*)T2b, N2, ssl + 2 * 1024, m2bng + l * 512, m2bnb + l * 512,
            U2b, 512, 0, nullptr, nullptr);
        // W2 GEMMs with fused column stats, both branches
        gemm_dual<<<dim3(192, 4), 256, 0, stream>>>(
            128,
            U1b, w2t1 + (size_t)l * 512 * 512, 512, Y1b, 512, 0, ssl + 1 * 1024,
            U2b, w2t2 + (size_t)l * 512 * 512, 512, Y2b, 512, 0, ssl + 3 * 1024);
        // final BN apply: b1 -> H1b[:, :512] * a0 with fused JK pooling; b2 -> H2b
        bn_apply2<<<1536, 128, 0, stream>>>(
            1024, gid,
            (const u16x4*)Y1b, N1, ssl + 1 * 1024, bn1g + l * 512, bn1b + l * 512,
            H1b, 1024, 0, aDev + 0, PLl,
            (const u16x4*)Y2b, N2, ssl + 3 * 1024, bn2g + l * 512, bn2b + l * 512,
            H2b, 512, 0, nullptr, nullptr);
        // fusion: h2A = motif2A^T @ h2 (split-K), finalize scales a1 + pools
        transpose_bf16<<<dim3(16, 128), dim3(32, 8), 0, stream>>>(H2b, H2t, N2, 512);
        gemm_splitk<<<dim3(64, 4, KS), 256, 0, stream>>>(motifT, H2t, N1, 512, 4096, Cpart);
        sumk_cvt_pool<<<1024, 128, 0, stream>>>((const f32x4*)Cpart, KS, aDev + 1,
                                                H1b, gid, PLl);
    }

    score_kernel<<<64, 256, 0, stream>>>(P0, PL, pW0, pb0, pW, pb, out);
}